// Round 13
// baseline (3448.202 us; speedup 1.0000x reference)
//
#include <hip/hip_runtime.h>
#include <hip/hip_bf16.h>

#define Bc 32
#define NPGc 290
#define Nn 9280
#define Ec 74240
#define LPc 900
#define INFc 75
#define Dd 128
#define HKc 768
#define LQ 885
#define CHT 128
#define S1 904
#define S2 896
#define S3 888

__global__ void k_sentinel(float* out, float val){
  int t = threadIdx.x;
  if (t < 128) out[t] = val;
}

// ---------------- GCN ----------------
__global__ void k_h0(float* __restrict__ h0, const float* __restrict__ nh, const float* __restrict__ Wi){
  int n = blockIdx.x, j = threadIdx.x;
  __shared__ float arow[INFc];
  if (j < INFc) arow[j] = nh[(size_t)n*INFc + j];
  __syncthreads();
  float s = 0.f;
  #pragma unroll 5
  for (int k=0;k<INFc;k++) s += arow[k]*Wi[(size_t)k*Dd + j];
  h0[(size_t)n*Dd + j] = s;
}

__global__ void k_build_adj(float* __restrict__ A, const int* __restrict__ src, const int* __restrict__ dst){
  int e = blockIdx.x*blockDim.x + threadIdx.x;
  if (e >= Ec) return;
  int s = src[e], d = dst[e];
  int b = d / NPGc;
  int dl = d - b*NPGc, sl = s - b*NPGc;
  atomicAdd(&A[((size_t)b*NPGc + dl)*NPGc + sl], 1.f);
}

__global__ void k_gcn_fused(float* __restrict__ out, const float* __restrict__ A, const float* __restrict__ h,
                            const float* __restrict__ W, const float* __restrict__ bvec,
                            const float* __restrict__ Wr, const float* __restrict__ br){
  int b = blockIdx.y;
  int i0 = blockIdx.x*8;
  int j = threadIdx.x;  // 128
  __shared__ float arow[8][NPGc];
  __shared__ float ar[8][Dd], hr[8][Dd];
  for (int idx=j; idx<8*NPGc; idx+=128){
    int r=idx/NPGc, c=idx-r*NPGc;
    arow[r][c] = (i0+r<NPGc) ? A[((size_t)b*NPGc+i0+r)*NPGc+c] : 0.f;
  }
  for (int idx=j; idx<8*Dd; idx+=128){
    int r=idx>>7, k=idx&127;
    hr[r][k] = (i0+r<NPGc) ? h[((size_t)b*NPGc+i0+r)*Dd+k] : 0.f;
  }
  __syncthreads();
  float acc[8]={};
  const float* hb = h + (size_t)b*NPGc*Dd + j;
  for (int c=0;c<NPGc;c++){
    float hv = hb[(size_t)c*Dd];
    #pragma unroll
    for (int r=0;r<8;r++) acc[r] += arow[r][c]*hv;
  }
  #pragma unroll
  for (int r=0;r<8;r++) ar[r][j] = acc[r];
  __syncthreads();
  float s1[8], s2[8];
  float bj = bvec[j], brj = br[j];
  #pragma unroll
  for (int r=0;r<8;r++){ s1[r]=bj; s2[r]=brj; }
  for (int k=0;k<Dd;k++){
    float wk = W[(size_t)k*Dd+j], wrk = Wr[(size_t)k*Dd+j];
    #pragma unroll
    for (int r=0;r<8;r++){ s1[r] += ar[r][k]*wk; s2[r] += hr[r][k]*wrk; }
  }
  int nr = NPGc - i0; if (nr > 8) nr = 8;
  for (int r=0;r<nr;r++)
    out[((size_t)b*NPGc+i0+r)*Dd + j] = fmaxf(s1[r],0.f) + fmaxf(s2[r],0.f);
}

// ---------------- ProteinCNN ----------------
__global__ void k_embed(float* __restrict__ x, const int* __restrict__ vp, const float* __restrict__ emb){
  int t = blockIdx.x*blockDim.x + threadIdx.x;
  int d = blockIdx.y, b = blockIdx.z;
  if (t >= LPc) return;
  int tok = vp[b*LPc + t];
  x[((size_t)b*Dd + d)*LPc + t] = emb[(size_t)tok*Dd + d];
}

__global__ void k_wT(float* __restrict__ wT, const float* __restrict__ w, int KW){
  int idx = blockIdx.x*256 + threadIdx.x;
  int tot = Dd*Dd*KW;
  if (idx >= tot) return;
  int o = idx & 127; int rest = idx >> 7;
  wT[(size_t)rest*Dd + o] = w[((size_t)o*Dd + rest/KW)*KW + (rest % KW)];
}

// conv GEMM: M=128(o) x N=64(t), 8x4/thread, BN-apply fused on input (scale/shift, nullable)
template<int KW>
__global__ void k_convg2(float* __restrict__ y, const float* __restrict__ x, const float* __restrict__ wT,
                         const float* __restrict__ cb, const float* __restrict__ scale,
                         const float* __restrict__ shift, int Lin, int Lout, int XS, int YS, int cbo){
  int b = blockIdx.y;
  int t0 = blockIdx.x*64;
  __shared__ float As[16][128], Bs[16][64];
  int tid=threadIdx.x, tx=tid&15, ty=tid>>4;
  int ldr=tid>>4;
  int ldc8=(tid&15)*8, ldc4=(tid&15)*4;
  float acc[8][4]={};
  const int KT = Dd*KW;
  for (int k0=0; k0<KT; k0+=16){
    *(float4*)&As[ldr][ldc8]   = *(const float4*)(wT + (size_t)(k0+ldr)*Dd + ldc8);
    *(float4*)&As[ldr][ldc8+4] = *(const float4*)(wT + (size_t)(k0+ldr)*Dd + ldc8+4);
    int kr = k0+ldr; int i = kr/KW, k = kr - i*KW;
    float sc_ = scale ? scale[i] : 1.f;
    float sh_ = shift ? shift[i] : 0.f;
    const float* xr = x + ((size_t)b*Dd + i)*XS + t0 + k + ldc4;
    int tb = t0 + k + ldc4;
    Bs[ldr][ldc4+0] = (tb+0 < Lin) ? xr[0]*sc_+sh_ : 0.f;
    Bs[ldr][ldc4+1] = (tb+1 < Lin) ? xr[1]*sc_+sh_ : 0.f;
    Bs[ldr][ldc4+2] = (tb+2 < Lin) ? xr[2]*sc_+sh_ : 0.f;
    Bs[ldr][ldc4+3] = (tb+3 < Lin) ? xr[3]*sc_+sh_ : 0.f;
    __syncthreads();
    #pragma unroll
    for (int kk=0;kk<16;kk++){
      float a[8], bb[4];
      *(float4*)&a[0] = *(const float4*)&As[kk][ty*4];
      *(float4*)&a[4] = *(const float4*)&As[kk][64+ty*4];
      *(float4*)bb = *(const float4*)&Bs[kk][tx*4];
      #pragma unroll
      for (int i2=0;i2<8;i2++)
        #pragma unroll
        for (int j2=0;j2<4;j2++) acc[i2][j2] += a[i2]*bb[j2];
    }
    __syncthreads();
  }
  int t = t0 + tx*4;
  #pragma unroll
  for (int i2=0;i2<8;i2++){
    int o = (i2<4) ? ty*4+i2 : 64+ty*4+(i2-4);
    float bias = cb[cbo+o];
    float* yp = y + ((size_t)b*Dd+o)*YS + t;
    if (t+3 < Lout){
      float4 v;
      v.x=fmaxf(acc[i2][0]+bias,0.f); v.y=fmaxf(acc[i2][1]+bias,0.f);
      v.z=fmaxf(acc[i2][2]+bias,0.f); v.w=fmaxf(acc[i2][3]+bias,0.f);
      *(float4*)yp = v;
    } else {
      for (int j2=0;j2<4;j2++) if (t+j2 < Lout) yp[j2] = fmaxf(acc[i2][j2]+bias,0.f);
    }
  }
}

// stats -> scale/shift (BN fold)
__global__ void k_bnc_stats2(float* __restrict__ scale, float* __restrict__ shift,
                             const float* __restrict__ y, int Lout, int YS,
                             const float* __restrict__ g, const float* __restrict__ bb, int go){
  int c = blockIdx.x;
  float s=0.f, ss=0.f;
  int cnt = Bc*Lout;
  for (int i = threadIdx.x; i < cnt; i += blockDim.x){
    int b = i / Lout, t = i - b*Lout;
    float v = y[((size_t)b*Dd+c)*YS + t];
    s += v; ss += v*v;
  }
  __shared__ float rs[256], rss[256];
  rs[threadIdx.x]=s; rss[threadIdx.x]=ss; __syncthreads();
  for (int st=128; st>0; st>>=1){
    if (threadIdx.x<st){ rs[threadIdx.x]+=rs[threadIdx.x+st]; rss[threadIdx.x]+=rss[threadIdx.x+st]; }
    __syncthreads();
  }
  if (threadIdx.x==0){
    float m = rs[0]/cnt; float v = rss[0]/cnt - m*m; if (v<0.f) v=0.f;
    float r = rsqrtf(v+1e-5f);
    float scl = r*g[go+c];
    scale[c] = scl;
    shift[c] = bb[go+c] - m*scl;
  }
}

// ---------------- BAN Gram path ----------------
// q chunk GEMM: M=128(t) x N=64(j), 8x4/thread, BN fused on x
__global__ void k_qgemm2(float* __restrict__ qc, const float* __restrict__ x,
                         const float* __restrict__ W, const float* __restrict__ bias,
                         const float* __restrict__ scale, const float* __restrict__ shift,
                         int t0c, int Tc){
  int b = blockIdx.z;
  int n0 = blockIdx.x*64;
  __shared__ float As[16][128], Bs[16][64];
  int tid=threadIdx.x, tx=tid&15, ty=tid>>4;
  int ldr=tid>>4;
  int ldc8=(tid&15)*8, ldc4=(tid&15)*4;
  float acc[8][4]={};
  for (int k0=0; k0<Dd; k0+=16){
    int d = k0+ldr;
    float sc_ = scale[d], sh_ = shift[d];
    const float* xr = x + ((size_t)b*Dd + d)*S3 + t0c + ldc8;
    #pragma unroll
    for (int u=0;u<8;u++){
      int m = ldc8+u;
      As[ldr][m] = (m < Tc) ? (xr[u]*sc_+sh_) : 0.f;
    }
    *(float4*)&Bs[ldr][ldc4] = *(const float4*)(W + (size_t)d*HKc + n0 + ldc4);
    __syncthreads();
    #pragma unroll
    for (int kk=0;kk<16;kk++){
      float a[8], bb[4];
      *(float4*)&a[0] = *(const float4*)&As[kk][ty*4];
      *(float4*)&a[4] = *(const float4*)&As[kk][64+ty*4];
      *(float4*)bb = *(const float4*)&Bs[kk][tx*4];
      #pragma unroll
      for (int i2=0;i2<8;i2++)
        #pragma unroll
        for (int j2=0;j2<4;j2++) acc[i2][j2] += a[i2]*bb[j2];
    }
    __syncthreads();
  }
  int n = n0 + tx*4;
  float4 b4 = *(const float4*)(bias + n);
  #pragma unroll
  for (int i2=0;i2<8;i2++){
    int m = (i2<4) ? ty*4+i2 : 64+ty*4+(i2-4);
    if (m >= Tc) continue;
    float4 o;
    o.x = fmaxf(acc[i2][0]+b4.x,0.f);
    o.y = fmaxf(acc[i2][1]+b4.y,0.f);
    o.z = fmaxf(acc[i2][2]+b4.z,0.f);
    o.w = fmaxf(acc[i2][3]+b4.w,0.f);
    *(float4*)(qc + ((size_t)b*CHT + m)*HKc + n) = o;
  }
}

__global__ void k_colsum_acc(float* __restrict__ S, const float* __restrict__ X, int Tc, int store){
  int j = blockIdx.x*blockDim.x + threadIdx.x;
  int b = blockIdx.y;
  if (j >= HKc) return;
  const float* p = X + (size_t)b*CHT*HKc + j;
  float s=0.f;
  for (int t=0;t<Tc;t++) s += p[(size_t)t*HKc];
  if (store) S[b*HKc + j] = s; else S[b*HKc + j] += s;
}

// Gq 128x128 upper-triangle tiles (6x6 -> 21), 8x8/thread split-64
__global__ void k_gram_acc2(float* __restrict__ G, const float* __restrict__ X, int Tc, int store){
  int b = blockIdx.y;
  int tl = blockIdx.x; int ti=0;
  while (tl >= 6-ti){ tl -= 6-ti; ti++; }
  int tj = ti + tl;
  int r0 = ti*128, c0 = tj*128;
  const float* Xb = X + (size_t)b*CHT*HKc;
  float* Gb = G + (size_t)b*HKc*HKc;
  __shared__ float As[16][128], Bs[16][128];
  int tid=threadIdx.x, tx=tid&15, ty=tid>>4;
  int ldr=tid>>4, ldc8=(tid&15)*8;
  float acc[8][8]={};
  for (int t0=0; t0<Tc; t0+=16){
    if (t0+ldr < Tc){
      const float* row = Xb + (size_t)(t0+ldr)*HKc;
      *(float4*)&As[ldr][ldc8]   = *(const float4*)(row + r0 + ldc8);
      *(float4*)&As[ldr][ldc8+4] = *(const float4*)(row + r0 + ldc8+4);
      *(float4*)&Bs[ldr][ldc8]   = *(const float4*)(row + c0 + ldc8);
      *(float4*)&Bs[ldr][ldc8+4] = *(const float4*)(row + c0 + ldc8+4);
    } else {
      float4 z = make_float4(0,0,0,0);
      *(float4*)&As[ldr][ldc8] = z; *(float4*)&As[ldr][ldc8+4] = z;
      *(float4*)&Bs[ldr][ldc8] = z; *(float4*)&Bs[ldr][ldc8+4] = z;
    }
    __syncthreads();
    #pragma unroll
    for (int kk=0;kk<16;kk++){
      float a[8], bb[8];
      *(float4*)&a[0] = *(const float4*)&As[kk][ty*4];
      *(float4*)&a[4] = *(const float4*)&As[kk][64+ty*4];
      *(float4*)&bb[0] = *(const float4*)&Bs[kk][tx*4];
      *(float4*)&bb[4] = *(const float4*)&Bs[kk][64+tx*4];
      #pragma unroll
      for (int i=0;i<8;i++)
        #pragma unroll
        for (int j=0;j<8;j++) acc[i][j] += a[i]*bb[j];
    }
    __syncthreads();
  }
  #pragma unroll
  for (int i=0;i<8;i++){
    int r = r0 + ((i<4) ? ty*4+i : 64+ty*4+(i-4));
    float* gp0 = Gb + (size_t)r*HKc + c0 + tx*4;
    float* gp1 = Gb + (size_t)r*HKc + c0 + 64 + tx*4;
    if (store){
      *(float4*)gp0 = make_float4(acc[i][0],acc[i][1],acc[i][2],acc[i][3]);
      *(float4*)gp1 = make_float4(acc[i][4],acc[i][5],acc[i][6],acc[i][7]);
    } else {
      float4 o0 = *(const float4*)gp0, o1 = *(const float4*)gp1;
      o0.x+=acc[i][0]; o0.y+=acc[i][1]; o0.z+=acc[i][2]; o0.w+=acc[i][3];
      o1.x+=acc[i][4]; o1.y+=acc[i][5]; o1.z+=acc[i][6]; o1.w+=acc[i][7];
      *(float4*)gp0 = o0; *(float4*)gp1 = o1;
    }
  }
}

__global__ void k_vgemm8(float* __restrict__ v, const float* __restrict__ vd,
                         const float* __restrict__ W, const float* __restrict__ bias, int rbase){
  int j = blockIdx.x*256 + threadIdx.x;
  int r0 = blockIdx.y*8;
  __shared__ float xr[8][Dd];
  for (int idx=threadIdx.x; idx<8*Dd; idx+=256){
    int r = idx>>7, k = idx&127;
    xr[r][k] = vd[(size_t)(rbase + r0 + r)*Dd + k];
  }
  __syncthreads();
  float acc[8];
  float bj = bias[j];
  #pragma unroll
  for (int r=0;r<8;r++) acc[r]=bj;
  for (int k=0;k<Dd;k++){
    float wk = W[(size_t)k*HKc+j];
    #pragma unroll
    for (int r=0;r<8;r++) acc[r] += xr[r][k]*wk;
  }
  #pragma unroll
  for (int r=0;r<8;r++)
    v[(size_t)(r0+r)*HKc + j] = fmaxf(acc[r],0.f);
}

__global__ void k_colsum_v(float* __restrict__ S, const float* __restrict__ X, int bbase){
  int j = blockIdx.x*blockDim.x + threadIdx.x;
  int bl = blockIdx.y;
  if (j >= HKc) return;
  const float* p = X + (size_t)bl*NPGc*HKc + j;
  float s=0.f;
  for (int t=0;t<NPGc;t++) s += p[(size_t)t*HKc];
  S[(bbase+bl)*HKc + j] = s;
}

// gramf 128x128 triangle tiles, 8x8/thread; row+col reductions
__global__ void k_gramf2(float* __restrict__ f, const float* __restrict__ V,
                         const float* __restrict__ Gq_, const float* __restrict__ hm, int bbase){
  int bl = blockIdx.z, bg = bbase + bl;
  int tl = blockIdx.x; int ti=0;
  while (tl >= 6-ti){ tl -= 6-ti; ti++; }
  int tj = ti + tl;
  int r0 = ti*128, c0 = tj*128;
  int offdiag = (ti != tj);
  const float* Vb = V + (size_t)bl*NPGc*HKc;
  __shared__ float As[16][128], Bs[16][128];
  __shared__ float wc[128], wr[128];
  int tid=threadIdx.x, tx=tid&15, ty=tid>>4;
  int ldr=tid>>4, ldc8=(tid&15)*8;
  if (tid < 128) wc[tid] = hm[c0+tid] + hm[HKc + c0 + tid];
  else { int t2 = tid-128; wr[t2] = hm[r0+t2] + hm[HKc + r0 + t2]; }
  float acc[8][8]={};
  for (int t0=0; t0<NPGc; t0+=16){
    if (t0+ldr < NPGc){
      const float* row = Vb + (size_t)(t0+ldr)*HKc;
      *(float4*)&As[ldr][ldc8]   = *(const float4*)(row + r0 + ldc8);
      *(float4*)&As[ldr][ldc8+4] = *(const float4*)(row + r0 + ldc8+4);
      *(float4*)&Bs[ldr][ldc8]   = *(const float4*)(row + c0 + ldc8);
      *(float4*)&Bs[ldr][ldc8+4] = *(const float4*)(row + c0 + ldc8+4);
    } else {
      float4 z = make_float4(0,0,0,0);
      *(float4*)&As[ldr][ldc8] = z; *(float4*)&As[ldr][ldc8+4] = z;
      *(float4*)&Bs[ldr][ldc8] = z; *(float4*)&Bs[ldr][ldc8+4] = z;
    }
    __syncthreads();
    #pragma unroll
    for (int kk=0;kk<16;kk++){
      float a[8], bb[8];
      *(float4*)&a[0] = *(const float4*)&As[kk][ty*4];
      *(float4*)&a[4] = *(const float4*)&As[kk][64+ty*4];
      *(float4*)&bb[0] = *(const float4*)&Bs[kk][tx*4];
      *(float4*)&bb[4] = *(const float4*)&Bs[kk][64+tx*4];
      #pragma unroll
      for (int i=0;i<8;i++)
        #pragma unroll
        for (int j=0;j<8;j++) acc[i][j] += a[i]*bb[j];
    }
    __syncthreads();
  }
  const float* gqb = Gq_ + (size_t)bg*HKc*HKc;
  float wcl[8];
  #pragma unroll
  for (int j=0;j<4;j++){ wcl[j]=wc[tx*4+j]; wcl[4+j]=wc[64+tx*4+j]; }
  float cp[8] = {0,0,0,0,0,0,0,0};
  #pragma unroll
  for (int i=0;i<8;i++){
    int lr = (i<4) ? ty*4+i : 64+ty*4+(i-4);
    int r = r0 + lr;
    float4 g0 = *(const float4*)(gqb + (size_t)r*HKc + c0 + tx*4);
    float4 g1 = *(const float4*)(gqb + (size_t)r*HKc + c0 + 64 + tx*4);
    float s = acc[i][0]*wcl[0]*g0.x + acc[i][1]*wcl[1]*g0.y
            + acc[i][2]*wcl[2]*g0.z + acc[i][3]*wcl[3]*g0.w
            + acc[i][4]*wcl[4]*g1.x + acc[i][5]*wcl[5]*g1.y
            + acc[i][6]*wcl[6]*g1.z + acc[i][7]*wcl[7]*g1.w;
    s += __shfl_xor(s,1); s += __shfl_xor(s,2);
    s += __shfl_xor(s,4); s += __shfl_xor(s,8);
    if (tx==0) atomicAdd(&f[bg*HKc + r], s);
    if (offdiag){
      float wri = wr[lr];
      cp[0]+=acc[i][0]*wri*g0.x; cp[1]+=acc[i][1]*wri*g0.y;
      cp[2]+=acc[i][2]*wri*g0.z; cp[3]+=acc[i][3]*wri*g0.w;
      cp[4]+=acc[i][4]*wri*g1.x; cp[5]+=acc[i][5]*wri*g1.y;
      cp[6]+=acc[i][6]*wri*g1.z; cp[7]+=acc[i][7]*wri*g1.w;
    }
  }
  if (offdiag){
    float (*colpart)[128] = (float(*)[128])As;  // reuse As LDS
    __syncthreads();
    #pragma unroll
    for (int j=0;j<4;j++){
      colpart[ty][tx*4+j] = cp[j];
      colpart[ty][64+tx*4+j] = cp[4+j];
    }
    __syncthreads();
    if (tid < 128){
      float s = 0.f;
      #pragma unroll
      for (int g2=0; g2<16; g2++) s += colpart[g2][tid];
      atomicAdd(&f[bg*HKc + c0 + tid], s);
    }
  }
}

// batched pool over 3 views
__global__ void k_pool3(float* __restrict__ fp, const float* __restrict__ f3,
                        const float* __restrict__ Sv3, const float* __restrict__ Sq,
                        const float* __restrict__ hb){
  int idx = blockIdx.x*256 + threadIdx.x;
  if (idx >= 3*Bc*256) return;
  int v = idx >> 13;
  int rem = idx & 8191;
  int b = rem >> 8, c = rem & 255;
  const float* f = f3 + (size_t)v*Bc*HKc;
  const float* Sv = Sv3 + (size_t)v*Bc*HKc;
  float hbs = hb[0] + hb[1];
  float s = 0.f;
  #pragma unroll
  for (int r=0;r<3;r++){
    int k = c*3 + r;
    s += f[b*HKc + k] + hbs*Sv[b*HKc + k]*Sq[b*HKc + k];
  }
  fp[idx] = s;
}

// batched BN over 3 views: grid (C, 3), 32 threads (batch)
__global__ void k_bnfeat3(float* __restrict__ y, const float* __restrict__ x, const float* __restrict__ g,
                          const float* __restrict__ bb, int C){
  int c = blockIdx.x; int v = blockIdx.y; int b = threadIdx.x;
  __shared__ float buf[32];
  __shared__ float mv[2];
  int row = v*32 + b;
  float val = x[(size_t)row*C + c];
  buf[b] = val;
  __syncthreads();
  if (b == 0){
    float s = 0.f;
    for (int i=0;i<32;i++) s += buf[i];
    float m = s/32.f;
    float vs = 0.f;
    for (int i=0;i<32;i++){ float d = buf[i]-m; vs += d*d; }
    mv[0] = m; mv[1] = vs/32.f;
  }
  __syncthreads();
  y[(size_t)row*C + c] = (val - mv[0])*rsqrtf(mv[1]+1e-5f)*g[c] + bb[c];
}

__global__ void k_mlp(float* __restrict__ out, const float* __restrict__ in, const float* __restrict__ W,
                      const float* __restrict__ bias, int K, int Nc, int doRelu){
  int b = blockIdx.y;   // 96 rows
  int j = blockIdx.x*blockDim.x + threadIdx.x;
  __shared__ float xr[512];
  for (int k=threadIdx.x; k<K; k+=blockDim.x) xr[k] = in[(size_t)b*K+k];
  __syncthreads();
  if (j >= Nc) return;
  float s = bias[j];
  for (int k=0;k<K;k++) s += xr[k]*W[(size_t)k*Nc + j];
  if (doRelu) s = fmaxf(s, 0.f);
  out[(size_t)b*Nc + j] = s;
}

__global__ void k_score96(float* __restrict__ sc, const float* __restrict__ h, const float* __restrict__ w,
                          const float* __restrict__ bb){
  int b = threadIdx.x; if (b>=96) return;
  float s = bb[0];
  for (int k=0;k<Dd;k++) s += h[(size_t)b*Dd+k]*w[k];
  sc[b] = s;
}

__global__ void k_out(float* __restrict__ out, const float* __restrict__ scores){
  int t = threadIdx.x;
  __shared__ float loss_s;
  if (t == 0){
    float sn1[32], sn2[32];
    for (int i=0;i<32;i++){
      float a = scores[32+i]; sn1[i] = a / fmaxf(fabsf(a), 1e-12f);
      float c = scores[64+i]; sn2[i] = c / fmaxf(fabsf(c), 1e-12f);
    }
    float acc = 0.f;
    for (int i=0;i<32;i++){
      float mx = -1e30f;
      for (int j=0;j<32;j++) mx = fmaxf(mx, sn1[i]*sn2[j]);
      float se = 0.f;
      for (int j=0;j<32;j++) se += expf(sn1[i]*sn2[j]-mx);
      acc += sn1[i]*sn2[i] - (mx + logf(se));
    }
    loss_s = -acc/32.f;
  }
  __syncthreads();
  out[t*4+0] = scores[t];
  out[t*4+1] = scores[32+t];
  out[t*4+2] = scores[64+t];
  out[t*4+3] = loss_s;
}

extern "C" void kernel_launch(void* const* d_in, const int* in_sizes, int n_in,
                              void* d_out, int out_size, void* d_ws, size_t ws_size,
                              hipStream_t stream){
  static const int exp_sizes[38] = {
    Nn*INFc, Ec, Ec, Bc*LPc, INFc*Dd,
    9*Dd*Dd, 9*Dd, 9*Dd*Dd, 9*Dd,
    26*Dd, Dd*Dd*3, Dd*Dd*6, Dd*Dd*9, 3*Dd, 3*Dd, 3*Dd,
    Dd*HKc, HKc, Dd*HKc, HKc, 2*HKc, 2, 256, 256,
    256*512, 512, 512*512, 512, 512*128, 128, 128, 1,
    512, 512, 512, 512, 128, 128 };
  if (n_in != 38){ k_sentinel<<<1,128,0,stream>>>((float*)d_out, 2000.f + n_in); return; }
  for (int i=0;i<38;i++){
    if (in_sizes[i] != exp_sizes[i]){
      k_sentinel<<<1,128,0,stream>>>((float*)d_out, 1000.f + i); return;
    }
  }

  const float* node_h=(const float*)d_in[0];
  const int*  esrc  =(const int*)d_in[1];
  const int*  edst  =(const int*)d_in[2];
  const int*  vp    =(const int*)d_in[3];
  const float* W_init=(const float*)d_in[4];
  const float* gcn_W =(const float*)d_in[5];
  const float* gcn_b =(const float*)d_in[6];
  const float* gcn_Wr=(const float*)d_in[7];
  const float* gcn_br=(const float*)d_in[8];
  const float* emb   =(const float*)d_in[9];
  const float* c1w=(const float*)d_in[10];
  const float* c2w=(const float*)d_in[11];
  const float* c3w=(const float*)d_in[12];
  const float* cbv=(const float*)d_in[13];
  const float* bng=(const float*)d_in[14];
  const float* bnb=(const float*)d_in[15];
  const float* Wv =(const float*)d_in[16];
  const float* bvv=(const float*)d_in[17];
  const float* Wq =(const float*)d_in[18];
  const float* bq =(const float*)d_in[19];
  const float* hmat =(const float*)d_in[20];
  const float* hbias=(const float*)d_in[21];
  const float* bang =(const float*)d_in[22];
  const float* banb =(const float*)d_in[23];
  const float* mw1=(const float*)d_in[24]; const float* mb1=(const float*)d_in[25];
  const float* mw2=(const float*)d_in[26]; const float* mb2=(const float*)d_in[27];
  const float* mw3=(const float*)d_in[28]; const float* mb3=(const float*)d_in[29];
  const float* mw4=(const float*)d_in[30]; const float* mb4=(const float*)d_in[31];
  const float* g1=(const float*)d_in[32]; const float* bb1=(const float*)d_in[33];
  const float* g2=(const float*)d_in[34]; const float* bb2=(const float*)d_in[35];
  const float* g3=(const float*)d_in[36]; const float* bb3=(const float*)d_in[37];

  float* ws = (float*)d_ws;
  size_t off = 0;
  auto alloc = [&](size_t n){ float* p = ws + off; off += n; return p; };

  const size_t NDsz = (size_t)Nn*Dd;              // 1,187,840
  const size_t CNNBP = (size_t)Bc*Dd*S1;          // 3,702,784
  const size_t ADJ  = (size_t)Bc*NPGc*NPGc;       // 2,691,200
  size_t ARENA = 4*NDsz + ADJ;                    // 7,442,560
  if (ARENA < 2*CNNBP) ARENA = 2*CNNBP;

  // smalls
  float* Sq   = alloc((size_t)Bc*HKc);
  float* Sv3  = alloc((size_t)3*Bc*HKc);
  float* fbuf3= alloc((size_t)3*Bc*HKc);
  float* fpool3=alloc((size_t)3*Bc*256);
  float* hh1  = alloc((size_t)96*512);
  float* hh2  = alloc((size_t)96*512);
  float* hh3  = alloc((size_t)96*128);
  float* sc   = alloc(96);
  float* scl1 = alloc(128); float* shf1 = alloc(128);
  float* scl2 = alloc(128); float* shf2 = alloc(128);
  float* scl3 = alloc(128); float* shf3 = alloc(128);
  float* wT1 = alloc((size_t)Dd*Dd*3);
  float* wT2 = alloc((size_t)Dd*Dd*6);
  float* wT3 = alloc((size_t)Dd*Dd*9);
  float* Gq  = alloc((size_t)Bc*HKc*HKc);
  float* arena = alloc(ARENA);

  // phase views
  float* cnnA = arena;
  float* cnnB = arena + CNNBP;
  float* qc   = arena + CNNBP;
  float* A0 = arena;
  float* A1 = arena + NDsz;
  float* A2t= arena + 2*NDsz;
  float* A3 = arena + 3*NDsz;
  // vbuf (16*290*768 = 3,563,520 floats) spans [NDsz, 4*NDsz) = A1+A2t+A3;
  // all three are dead by BAN time because h0 is recomputed per branch (r12 bug fix).
  float* vbuf = arena + NDsz;
  float* Adj  = arena + 4*NDsz;

  // ---- conv weight transposes ----
  k_wT<<<(Dd*Dd*3+255)/256,256,0,stream>>>(wT1, c1w, 3);
  k_wT<<<(Dd*Dd*6+255)/256,256,0,stream>>>(wT2, c2w, 6);
  k_wT<<<(Dd*Dd*9+255)/256,256,0,stream>>>(wT3, c3w, 9);

  // ---- ProteinCNN (BN folded into next stage-in) ----
  k_embed<<<dim3((LPc+127)/128, Dd, Bc),128,0,stream>>>(cnnB, vp, emb);
  k_convg2<3><<<dim3(15,Bc),256,0,stream>>>(cnnA, cnnB, wT1, cbv, nullptr, nullptr, 900, 898, 900, S1, 0);
  k_bnc_stats2<<<Dd,256,0,stream>>>(scl1, shf1, cnnA, 898, S1, bng, bnb, 0);
  k_convg2<6><<<dim3(14,Bc),256,0,stream>>>(cnnB, cnnA, wT2, cbv, scl1, shf1, 898, 893, S1, S2, 128);
  k_bnc_stats2<<<Dd,256,0,stream>>>(scl2, shf2, cnnB, 893, S2, bng, bnb, 128);
  k_convg2<9><<<dim3(14,Bc),256,0,stream>>>(cnnA, cnnB, wT3, cbv, scl2, shf2, 893, 885, S2, S3, 256);
  k_bnc_stats2<<<Dd,256,0,stream>>>(scl3, shf3, cnnA, 885, S3, bng, bnb, 256);

  // ---- q branch: chunked Gq (128-tile triangle) / Sq; BN3 fused into qgemm ----
  for (int t0c = 0, ci = 0; t0c < LQ; t0c += CHT, ci++){
    int Tc = LQ - t0c; if (Tc > CHT) Tc = CHT;
    k_qgemm2<<<dim3(12,1,Bc),256,0,stream>>>(qc, cnnA, Wq, bq, scl3, shf3, t0c, Tc);
    k_colsum_acc<<<dim3(3,Bc),256,0,stream>>>(Sq, qc, Tc, ci==0);
    k_gram_acc2<<<dim3(21,Bc),256,0,stream>>>(Gq, qc, Tc, ci==0);
  }

  // ---- dense adjacency ----
  hipMemsetAsync(Adj, 0, ADJ*sizeof(float), stream);
  k_build_adj<<<(Ec+255)/256,256,0,stream>>>(Adj, esrc, edst);

  hipMemsetAsync(fbuf3, 0, (size_t)3*Bc*HKc*sizeof(float), stream);

  // ---- three GCN branches + Gram-fused BAN (h0 recomputed per branch!) ----
  for (int g=0; g<3; g++){
    k_h0<<<Nn,Dd,0,stream>>>(A1, node_h, W_init);
    { int wo=g*3+0;
      k_gcn_fused<<<dim3(37,Bc),128,0,stream>>>(A3, Adj, A1, gcn_W+(size_t)wo*Dd*Dd, gcn_b+(size_t)wo*Dd,
                                                gcn_Wr+(size_t)wo*Dd*Dd, gcn_br+(size_t)wo*Dd); }
    { int wo=g*3+1;
      k_gcn_fused<<<dim3(37,Bc),128,0,stream>>>(A2t, Adj, A3, gcn_W+(size_t)wo*Dd*Dd, gcn_b+(size_t)wo*Dd,
                                                gcn_Wr+(size_t)wo*Dd*Dd, gcn_br+(size_t)wo*Dd); }
    { int wo=g*3+2;
      k_gcn_fused<<<dim3(37,Bc),128,0,stream>>>(A0, Adj, A2t, gcn_W+(size_t)wo*Dd*Dd, gcn_b+(size_t)wo*Dd,
                                                gcn_Wr+(size_t)wo*Dd*Dd, gcn_br+(size_t)wo*Dd); }

    for (int p=0; p<2; p++){
      int bbase = p*16;
      k_vgemm8<<<dim3(3,(16*NPGc)/8),256,0,stream>>>(vbuf, A0, Wv, bvv, bbase*NPGc);
      k_colsum_v<<<dim3(3,16),256,0,stream>>>(Sv3 + (size_t)g*Bc*HKc, vbuf, bbase);
      k_gramf2<<<dim3(21,1,16),256,0,stream>>>(fbuf3 + (size_t)g*Bc*HKc, vbuf, Gq, hmat, bbase);
    }
  }

  // ---- batched tail over 3 views (96 rows) ----
  k_pool3<<<(3*Bc*256+255)/256,256,0,stream>>>(fpool3, fbuf3, Sv3, Sq, hbias);
  k_bnfeat3<<<dim3(256,3),32,0,stream>>>(fpool3, fpool3, bang, banb, 256);
  k_mlp<<<dim3(2,96),256,0,stream>>>(hh1, fpool3, mw1, mb1, 256, 512, 1);
  k_bnfeat3<<<dim3(512,3),32,0,stream>>>(hh1, hh1, g1, bb1, 512);
  k_mlp<<<dim3(2,96),256,0,stream>>>(hh2, hh1, mw2, mb2, 512, 512, 1);
  k_bnfeat3<<<dim3(512,3),32,0,stream>>>(hh2, hh2, g2, bb2, 512);
  k_mlp<<<dim3(1,96),256,0,stream>>>(hh3, hh2, mw3, mb3, 512, 128, 1);
  k_bnfeat3<<<dim3(128,3),32,0,stream>>>(hh3, hh3, g3, bb3, 128);
  k_score96<<<1,96,0,stream>>>(sc, hh3, mw4, mb4);
  k_out<<<1,32,0,stream>>>((float*)d_out, sc);
}

// Round 14
// 3277.544 us; speedup vs baseline: 1.0521x; 1.0521x over previous
//
#include <hip/hip_runtime.h>
#include <hip/hip_bf16.h>

#define Bc 32
#define NPGc 290
#define Nn 9280
#define Ec 74240
#define LPc 900
#define INFc 75
#define Dd 128
#define HKc 768
#define LQ 885
#define CHT 128
#define S1 904
#define S2 896
#define S3 888
#define LP128 132   // padded LDS stride for 128-wide tiles (2-way banks, 16B aligned)

__global__ void k_sentinel(float* out, float val){
  int t = threadIdx.x;
  if (t < 128) out[t] = val;
}

// ---------------- GCN ----------------
__global__ void k_h0(float* __restrict__ h0, const float* __restrict__ nh, const float* __restrict__ Wi){
  int n = blockIdx.x, j = threadIdx.x;
  __shared__ float arow[INFc];
  if (j < INFc) arow[j] = nh[(size_t)n*INFc + j];
  __syncthreads();
  float s = 0.f;
  #pragma unroll 5
  for (int k=0;k<INFc;k++) s += arow[k]*Wi[(size_t)k*Dd + j];
  h0[(size_t)n*Dd + j] = s;
}

__global__ void k_build_adj(float* __restrict__ A, const int* __restrict__ src, const int* __restrict__ dst){
  int e = blockIdx.x*blockDim.x + threadIdx.x;
  if (e >= Ec) return;
  int s = src[e], d = dst[e];
  int b = d / NPGc;
  int dl = d - b*NPGc, sl = s - b*NPGc;
  atomicAdd(&A[((size_t)b*NPGc + dl)*NPGc + sl], 1.f);
}

__global__ void k_gcn_fused(float* __restrict__ out, const float* __restrict__ A, const float* __restrict__ h,
                            const float* __restrict__ W, const float* __restrict__ bvec,
                            const float* __restrict__ Wr, const float* __restrict__ br){
  int b = blockIdx.y;
  int i0 = blockIdx.x*8;
  int j = threadIdx.x;  // 128
  __shared__ float arow[8][NPGc];
  __shared__ float ar[8][Dd], hr[8][Dd];
  for (int idx=j; idx<8*NPGc; idx+=128){
    int r=idx/NPGc, c=idx-r*NPGc;
    arow[r][c] = (i0+r<NPGc) ? A[((size_t)b*NPGc+i0+r)*NPGc+c] : 0.f;
  }
  for (int idx=j; idx<8*Dd; idx+=128){
    int r=idx>>7, k=idx&127;
    hr[r][k] = (i0+r<NPGc) ? h[((size_t)b*NPGc+i0+r)*Dd+k] : 0.f;
  }
  __syncthreads();
  float acc[8]={};
  const float* hb = h + (size_t)b*NPGc*Dd + j;
  for (int c=0;c<NPGc;c++){
    float hv = hb[(size_t)c*Dd];
    #pragma unroll
    for (int r=0;r<8;r++) acc[r] += arow[r][c]*hv;
  }
  #pragma unroll
  for (int r=0;r<8;r++) ar[r][j] = acc[r];
  __syncthreads();
  float s1[8], s2[8];
  float bj = bvec[j], brj = br[j];
  #pragma unroll
  for (int r=0;r<8;r++){ s1[r]=bj; s2[r]=brj; }
  for (int k=0;k<Dd;k++){
    float wk = W[(size_t)k*Dd+j], wrk = Wr[(size_t)k*Dd+j];
    #pragma unroll
    for (int r=0;r<8;r++){ s1[r] += ar[r][k]*wk; s2[r] += hr[r][k]*wrk; }
  }
  int nr = NPGc - i0; if (nr > 8) nr = 8;
  for (int r=0;r<nr;r++)
    out[((size_t)b*NPGc+i0+r)*Dd + j] = fmaxf(s1[r],0.f) + fmaxf(s2[r],0.f);
}

// ---------------- ProteinCNN ----------------
__global__ void k_embed(float* __restrict__ x, const int* __restrict__ vp, const float* __restrict__ emb){
  int t = blockIdx.x*blockDim.x + threadIdx.x;
  int d = blockIdx.y, b = blockIdx.z;
  if (t >= LPc) return;
  int tok = vp[b*LPc + t];
  x[((size_t)b*Dd + d)*LPc + t] = emb[(size_t)tok*Dd + d];
}

__global__ void k_wT(float* __restrict__ wT, const float* __restrict__ w, int KW){
  int idx = blockIdx.x*256 + threadIdx.x;
  int tot = Dd*Dd*KW;
  if (idx >= tot) return;
  int o = idx & 127; int rest = idx >> 7;
  wT[(size_t)rest*Dd + o] = w[((size_t)o*Dd + rest/KW)*KW + (rest % KW)];
}

// conv GEMM: M=128(o) x N=64(t), 8x4/thread, padded As (LP128) -> no 4-way conflicts
template<int KW>
__global__ void k_convg2(float* __restrict__ y, const float* __restrict__ x, const float* __restrict__ wT,
                         const float* __restrict__ cb, const float* __restrict__ scale,
                         const float* __restrict__ shift, int Lin, int Lout, int XS, int YS, int cbo){
  int b = blockIdx.y;
  int t0 = blockIdx.x*64;
  __shared__ float As[16][LP128], Bs[16][64];
  int tid=threadIdx.x, tx=tid&15, ty=tid>>4;
  int ldr=tid>>4;
  int ldc8=(tid&15)*8, ldc4=(tid&15)*4;
  float acc[8][4]={};
  const int KT = Dd*KW;
  for (int k0=0; k0<KT; k0+=16){
    *(float4*)&As[ldr][ldc8]   = *(const float4*)(wT + (size_t)(k0+ldr)*Dd + ldc8);
    *(float4*)&As[ldr][ldc8+4] = *(const float4*)(wT + (size_t)(k0+ldr)*Dd + ldc8+4);
    int kr = k0+ldr; int i = kr/KW, k = kr - i*KW;
    float sc_ = scale ? scale[i] : 1.f;
    float sh_ = shift ? shift[i] : 0.f;
    const float* xr = x + ((size_t)b*Dd + i)*XS + t0 + k + ldc4;
    int tb = t0 + k + ldc4;
    Bs[ldr][ldc4+0] = (tb+0 < Lin) ? xr[0]*sc_+sh_ : 0.f;
    Bs[ldr][ldc4+1] = (tb+1 < Lin) ? xr[1]*sc_+sh_ : 0.f;
    Bs[ldr][ldc4+2] = (tb+2 < Lin) ? xr[2]*sc_+sh_ : 0.f;
    Bs[ldr][ldc4+3] = (tb+3 < Lin) ? xr[3]*sc_+sh_ : 0.f;
    __syncthreads();
    #pragma unroll
    for (int kk=0;kk<16;kk++){
      float a[8], bb[4];
      *(float4*)&a[0] = *(const float4*)&As[kk][ty*4];
      *(float4*)&a[4] = *(const float4*)&As[kk][64+ty*4];
      *(float4*)bb = *(const float4*)&Bs[kk][tx*4];
      #pragma unroll
      for (int i2=0;i2<8;i2++)
        #pragma unroll
        for (int j2=0;j2<4;j2++) acc[i2][j2] += a[i2]*bb[j2];
    }
    __syncthreads();
  }
  int t = t0 + tx*4;
  #pragma unroll
  for (int i2=0;i2<8;i2++){
    int o = (i2<4) ? ty*4+i2 : 64+ty*4+(i2-4);
    float bias = cb[cbo+o];
    float* yp = y + ((size_t)b*Dd+o)*YS + t;
    if (t+3 < Lout){
      float4 v;
      v.x=fmaxf(acc[i2][0]+bias,0.f); v.y=fmaxf(acc[i2][1]+bias,0.f);
      v.z=fmaxf(acc[i2][2]+bias,0.f); v.w=fmaxf(acc[i2][3]+bias,0.f);
      *(float4*)yp = v;
    } else {
      for (int j2=0;j2<4;j2++) if (t+j2 < Lout) yp[j2] = fmaxf(acc[i2][j2]+bias,0.f);
    }
  }
}

// stats -> scale/shift (BN fold)
__global__ void k_bnc_stats2(float* __restrict__ scale, float* __restrict__ shift,
                             const float* __restrict__ y, int Lout, int YS,
                             const float* __restrict__ g, const float* __restrict__ bb, int go){
  int c = blockIdx.x;
  float s=0.f, ss=0.f;
  int cnt = Bc*Lout;
  for (int i = threadIdx.x; i < cnt; i += blockDim.x){
    int b = i / Lout, t = i - b*Lout;
    float v = y[((size_t)b*Dd+c)*YS + t];
    s += v; ss += v*v;
  }
  __shared__ float rs[256], rss[256];
  rs[threadIdx.x]=s; rss[threadIdx.x]=ss; __syncthreads();
  for (int st=128; st>0; st>>=1){
    if (threadIdx.x<st){ rs[threadIdx.x]+=rs[threadIdx.x+st]; rss[threadIdx.x]+=rss[threadIdx.x+st]; }
    __syncthreads();
  }
  if (threadIdx.x==0){
    float m = rs[0]/cnt; float v = rss[0]/cnt - m*m; if (v<0.f) v=0.f;
    float r = rsqrtf(v+1e-5f);
    float scl = r*g[go+c];
    scale[c] = scl;
    shift[c] = bb[go+c] - m*scl;
  }
}

// ---------------- BAN Gram path (tiered, unified kernels) ----------------
// q GEMM window: rows [t0c, t0c+Tc) of graphs [bbase, bbase+nb); qc rows at stride R
__global__ void k_qgemmF(float* __restrict__ qc, const float* __restrict__ x,
                         const float* __restrict__ W, const float* __restrict__ bias,
                         const float* __restrict__ scale, const float* __restrict__ shift,
                         int bbase, int t0c, int Tc, int R){
  int bl = blockIdx.z, b = bbase + bl;
  int n0 = blockIdx.x*64;
  int m0 = blockIdx.y*128;
  __shared__ float As[16][LP128], Bs[16][64];
  int tid=threadIdx.x, tx=tid&15, ty=tid>>4;
  int ldr=tid>>4;
  int ldc8=(tid&15)*8, ldc4=(tid&15)*4;
  float acc[8][4]={};
  for (int k0=0; k0<Dd; k0+=16){
    int d = k0+ldr;
    float sc_ = scale[d], sh_ = shift[d];
    const float* xr = x + ((size_t)b*Dd + d)*S3 + t0c + m0 + ldc8;
    #pragma unroll
    for (int u=0;u<8;u++){
      int m = m0 + ldc8 + u;
      As[ldr][ldc8+u] = (m < Tc) ? (xr[u]*sc_+sh_) : 0.f;
    }
    *(float4*)&Bs[ldr][ldc4] = *(const float4*)(W + (size_t)d*HKc + n0 + ldc4);
    __syncthreads();
    #pragma unroll
    for (int kk=0;kk<16;kk++){
      float a[8], bb[4];
      *(float4*)&a[0] = *(const float4*)&As[kk][ty*4];
      *(float4*)&a[4] = *(const float4*)&As[kk][64+ty*4];
      *(float4*)bb = *(const float4*)&Bs[kk][tx*4];
      #pragma unroll
      for (int i2=0;i2<8;i2++)
        #pragma unroll
        for (int j2=0;j2<4;j2++) acc[i2][j2] += a[i2]*bb[j2];
    }
    __syncthreads();
  }
  int n = n0 + tx*4;
  float4 b4 = *(const float4*)(bias + n);
  #pragma unroll
  for (int i2=0;i2<8;i2++){
    int m = m0 + ((i2<4) ? ty*4+i2 : 64+ty*4+(i2-4));
    if (m >= Tc) continue;
    float4 o;
    o.x = fmaxf(acc[i2][0]+b4.x,0.f);
    o.y = fmaxf(acc[i2][1]+b4.y,0.f);
    o.z = fmaxf(acc[i2][2]+b4.z,0.f);
    o.w = fmaxf(acc[i2][3]+b4.w,0.f);
    *(float4*)(qc + ((size_t)bl*R + m)*HKc + n) = o;
  }
}

__global__ void k_colsumF(float* __restrict__ S, const float* __restrict__ X,
                          int bbase, int Tc, int R, int store){
  int j = blockIdx.x*blockDim.x + threadIdx.x;
  int bl = blockIdx.y;
  if (j >= HKc) return;
  const float* p = X + (size_t)bl*R*HKc + j;
  float s=0.f;
  for (int t=0;t<Tc;t++) s += p[(size_t)t*HKc];
  int bg = bbase + bl;
  if (store) S[bg*HKc + j] = s; else S[bg*HKc + j] += s;
}

// Gq 128x128 upper-triangle tiles, 8x8/thread, padded LDS; single-shot when store=1
__global__ void k_gramF(float* __restrict__ G, const float* __restrict__ X,
                        int bbase, int Tc, int R, int store){
  int bl = blockIdx.y, bg = bbase + bl;
  int tl = blockIdx.x; int ti=0;
  while (tl >= 6-ti){ tl -= 6-ti; ti++; }
  int tj = ti + tl;
  int r0 = ti*128, c0 = tj*128;
  const float* Xb = X + (size_t)bl*R*HKc;
  float* Gb = G + (size_t)bg*HKc*HKc;
  __shared__ float As[16][LP128], Bs[16][LP128];
  int tid=threadIdx.x, tx=tid&15, ty=tid>>4;
  int ldr=tid>>4, ldc8=(tid&15)*8;
  float acc[8][8]={};
  for (int t0=0; t0<Tc; t0+=16){
    if (t0+ldr < Tc){
      const float* row = Xb + (size_t)(t0+ldr)*HKc;
      *(float4*)&As[ldr][ldc8]   = *(const float4*)(row + r0 + ldc8);
      *(float4*)&As[ldr][ldc8+4] = *(const float4*)(row + r0 + ldc8+4);
      *(float4*)&Bs[ldr][ldc8]   = *(const float4*)(row + c0 + ldc8);
      *(float4*)&Bs[ldr][ldc8+4] = *(const float4*)(row + c0 + ldc8+4);
    } else {
      float4 z = make_float4(0,0,0,0);
      *(float4*)&As[ldr][ldc8] = z; *(float4*)&As[ldr][ldc8+4] = z;
      *(float4*)&Bs[ldr][ldc8] = z; *(float4*)&Bs[ldr][ldc8+4] = z;
    }
    __syncthreads();
    #pragma unroll
    for (int kk=0;kk<16;kk++){
      float a[8], bb[8];
      *(float4*)&a[0] = *(const float4*)&As[kk][ty*4];
      *(float4*)&a[4] = *(const float4*)&As[kk][64+ty*4];
      *(float4*)&bb[0] = *(const float4*)&Bs[kk][tx*4];
      *(float4*)&bb[4] = *(const float4*)&Bs[kk][64+tx*4];
      #pragma unroll
      for (int i=0;i<8;i++)
        #pragma unroll
        for (int j=0;j<8;j++) acc[i][j] += a[i]*bb[j];
    }
    __syncthreads();
  }
  #pragma unroll
  for (int i=0;i<8;i++){
    int r = r0 + ((i<4) ? ty*4+i : 64+ty*4+(i-4));
    float* gp0 = Gb + (size_t)r*HKc + c0 + tx*4;
    float* gp1 = Gb + (size_t)r*HKc + c0 + 64 + tx*4;
    if (store){
      *(float4*)gp0 = make_float4(acc[i][0],acc[i][1],acc[i][2],acc[i][3]);
      *(float4*)gp1 = make_float4(acc[i][4],acc[i][5],acc[i][6],acc[i][7]);
    } else {
      float4 o0 = *(const float4*)gp0, o1 = *(const float4*)gp1;
      o0.x+=acc[i][0]; o0.y+=acc[i][1]; o0.z+=acc[i][2]; o0.w+=acc[i][3];
      o1.x+=acc[i][4]; o1.y+=acc[i][5]; o1.z+=acc[i][6]; o1.w+=acc[i][7];
      *(float4*)gp0 = o0; *(float4*)gp1 = o1;
    }
  }
}

__global__ void k_vgemm8(float* __restrict__ v, const float* __restrict__ vd,
                         const float* __restrict__ W, const float* __restrict__ bias, int rbase){
  int j = blockIdx.x*256 + threadIdx.x;
  int r0 = blockIdx.y*8;
  __shared__ float xr[8][Dd];
  for (int idx=threadIdx.x; idx<8*Dd; idx+=256){
    int r = idx>>7, k = idx&127;
    xr[r][k] = vd[(size_t)(rbase + r0 + r)*Dd + k];
  }
  __syncthreads();
  float acc[8];
  float bj = bias[j];
  #pragma unroll
  for (int r=0;r<8;r++) acc[r]=bj;
  for (int k=0;k<Dd;k++){
    float wk = W[(size_t)k*HKc+j];
    #pragma unroll
    for (int r=0;r<8;r++) acc[r] += xr[r][k]*wk;
  }
  #pragma unroll
  for (int r=0;r<8;r++)
    v[(size_t)(r0+r)*HKc + j] = fmaxf(acc[r],0.f);
}

__global__ void k_colsum_v(float* __restrict__ S, const float* __restrict__ X, int bbase){
  int j = blockIdx.x*blockDim.x + threadIdx.x;
  int bl = blockIdx.y;
  if (j >= HKc) return;
  const float* p = X + (size_t)bl*NPGc*HKc + j;
  float s=0.f;
  for (int t=0;t<NPGc;t++) s += p[(size_t)t*HKc];
  S[(bbase+bl)*HKc + j] = s;
}

// gramf 128x128 triangle tiles, 8x8/thread, padded LDS; row+col reductions
__global__ void k_gramf2(float* __restrict__ f, const float* __restrict__ V,
                         const float* __restrict__ Gq_, const float* __restrict__ hm, int bbase){
  int bl = blockIdx.z, bg = bbase + bl;
  int tl = blockIdx.x; int ti=0;
  while (tl >= 6-ti){ tl -= 6-ti; ti++; }
  int tj = ti + tl;
  int r0 = ti*128, c0 = tj*128;
  int offdiag = (ti != tj);
  const float* Vb = V + (size_t)bl*NPGc*HKc;
  __shared__ float As[16][LP128], Bs[16][LP128];
  __shared__ float wc[128], wr[128];
  int tid=threadIdx.x, tx=tid&15, ty=tid>>4;
  int ldr=tid>>4, ldc8=(tid&15)*8;
  if (tid < 128) wc[tid] = hm[c0+tid] + hm[HKc + c0 + tid];
  else { int t2 = tid-128; wr[t2] = hm[r0+t2] + hm[HKc + r0 + t2]; }
  float acc[8][8]={};
  for (int t0=0; t0<NPGc; t0+=16){
    if (t0+ldr < NPGc){
      const float* row = Vb + (size_t)(t0+ldr)*HKc;
      *(float4*)&As[ldr][ldc8]   = *(const float4*)(row + r0 + ldc8);
      *(float4*)&As[ldr][ldc8+4] = *(const float4*)(row + r0 + ldc8+4);
      *(float4*)&Bs[ldr][ldc8]   = *(const float4*)(row + c0 + ldc8);
      *(float4*)&Bs[ldr][ldc8+4] = *(const float4*)(row + c0 + ldc8+4);
    } else {
      float4 z = make_float4(0,0,0,0);
      *(float4*)&As[ldr][ldc8] = z; *(float4*)&As[ldr][ldc8+4] = z;
      *(float4*)&Bs[ldr][ldc8] = z; *(float4*)&Bs[ldr][ldc8+4] = z;
    }
    __syncthreads();
    #pragma unroll
    for (int kk=0;kk<16;kk++){
      float a[8], bb[8];
      *(float4*)&a[0] = *(const float4*)&As[kk][ty*4];
      *(float4*)&a[4] = *(const float4*)&As[kk][64+ty*4];
      *(float4*)&bb[0] = *(const float4*)&Bs[kk][tx*4];
      *(float4*)&bb[4] = *(const float4*)&Bs[kk][64+tx*4];
      #pragma unroll
      for (int i=0;i<8;i++)
        #pragma unroll
        for (int j=0;j<8;j++) acc[i][j] += a[i]*bb[j];
    }
    __syncthreads();
  }
  const float* gqb = Gq_ + (size_t)bg*HKc*HKc;
  float wcl[8];
  #pragma unroll
  for (int j=0;j<4;j++){ wcl[j]=wc[tx*4+j]; wcl[4+j]=wc[64+tx*4+j]; }
  float cp[8] = {0,0,0,0,0,0,0,0};
  #pragma unroll
  for (int i=0;i<8;i++){
    int lr = (i<4) ? ty*4+i : 64+ty*4+(i-4);
    int r = r0 + lr;
    float4 g0 = *(const float4*)(gqb + (size_t)r*HKc + c0 + tx*4);
    float4 g1 = *(const float4*)(gqb + (size_t)r*HKc + c0 + 64 + tx*4);
    float s = acc[i][0]*wcl[0]*g0.x + acc[i][1]*wcl[1]*g0.y
            + acc[i][2]*wcl[2]*g0.z + acc[i][3]*wcl[3]*g0.w
            + acc[i][4]*wcl[4]*g1.x + acc[i][5]*wcl[5]*g1.y
            + acc[i][6]*wcl[6]*g1.z + acc[i][7]*wcl[7]*g1.w;
    s += __shfl_xor(s,1); s += __shfl_xor(s,2);
    s += __shfl_xor(s,4); s += __shfl_xor(s,8);
    if (tx==0) atomicAdd(&f[bg*HKc + r], s);
    if (offdiag){
      float wri = wr[lr];
      cp[0]+=acc[i][0]*wri*g0.x; cp[1]+=acc[i][1]*wri*g0.y;
      cp[2]+=acc[i][2]*wri*g0.z; cp[3]+=acc[i][3]*wri*g0.w;
      cp[4]+=acc[i][4]*wri*g1.x; cp[5]+=acc[i][5]*wri*g1.y;
      cp[6]+=acc[i][6]*wri*g1.z; cp[7]+=acc[i][7]*wri*g1.w;
    }
  }
  if (offdiag){
    float (*colpart)[128] = (float(*)[128])As;  // reuse As LDS (16*132 >= 16*128)
    __syncthreads();
    #pragma unroll
    for (int j=0;j<4;j++){
      colpart[ty][tx*4+j] = cp[j];
      colpart[ty][64+tx*4+j] = cp[4+j];
    }
    __syncthreads();
    if (tid < 128){
      float s = 0.f;
      #pragma unroll
      for (int g2=0; g2<16; g2++) s += colpart[g2][tid];
      atomicAdd(&f[bg*HKc + c0 + tid], s);
    }
  }
}

// batched pool over 3 views
__global__ void k_pool3(float* __restrict__ fp, const float* __restrict__ f3,
                        const float* __restrict__ Sv3, const float* __restrict__ Sq,
                        const float* __restrict__ hb){
  int idx = blockIdx.x*256 + threadIdx.x;
  if (idx >= 3*Bc*256) return;
  int v = idx >> 13;
  int rem = idx & 8191;
  int b = rem >> 8, c = rem & 255;
  const float* f = f3 + (size_t)v*Bc*HKc;
  const float* Sv = Sv3 + (size_t)v*Bc*HKc;
  float hbs = hb[0] + hb[1];
  float s = 0.f;
  #pragma unroll
  for (int r=0;r<3;r++){
    int k = c*3 + r;
    s += f[b*HKc + k] + hbs*Sv[b*HKc + k]*Sq[b*HKc + k];
  }
  fp[idx] = s;
}

// batched BN over 3 views
__global__ void k_bnfeat3(float* __restrict__ y, const float* __restrict__ x, const float* __restrict__ g,
                          const float* __restrict__ bb, int C){
  int c = blockIdx.x; int v = blockIdx.y; int b = threadIdx.x;
  __shared__ float buf[32];
  __shared__ float mv[2];
  int row = v*32 + b;
  float val = x[(size_t)row*C + c];
  buf[b] = val;
  __syncthreads();
  if (b == 0){
    float s = 0.f;
    for (int i=0;i<32;i++) s += buf[i];
    float m = s/32.f;
    float vs = 0.f;
    for (int i=0;i<32;i++){ float d = buf[i]-m; vs += d*d; }
    mv[0] = m; mv[1] = vs/32.f;
  }
  __syncthreads();
  y[(size_t)row*C + c] = (val - mv[0])*rsqrtf(mv[1]+1e-5f)*g[c] + bb[c];
}

__global__ void k_mlp(float* __restrict__ out, const float* __restrict__ in, const float* __restrict__ W,
                      const float* __restrict__ bias, int K, int Nc, int doRelu){
  int b = blockIdx.y;   // 96 rows
  int j = blockIdx.x*blockDim.x + threadIdx.x;
  __shared__ float xr[512];
  for (int k=threadIdx.x; k<K; k+=blockDim.x) xr[k] = in[(size_t)b*K+k];
  __syncthreads();
  if (j >= Nc) return;
  float s = bias[j];
  for (int k=0;k<K;k++) s += xr[k]*W[(size_t)k*Nc + j];
  if (doRelu) s = fmaxf(s, 0.f);
  out[(size_t)b*Nc + j] = s;
}

__global__ void k_score96(float* __restrict__ sc, const float* __restrict__ h, const float* __restrict__ w,
                          const float* __restrict__ bb){
  int b = threadIdx.x; if (b>=96) return;
  float s = bb[0];
  for (int k=0;k<Dd;k++) s += h[(size_t)b*Dd+k]*w[k];
  sc[b] = s;
}

__global__ void k_out(float* __restrict__ out, const float* __restrict__ scores){
  int t = threadIdx.x;
  __shared__ float loss_s;
  if (t == 0){
    float sn1[32], sn2[32];
    for (int i=0;i<32;i++){
      float a = scores[32+i]; sn1[i] = a / fmaxf(fabsf(a), 1e-12f);
      float c = scores[64+i]; sn2[i] = c / fmaxf(fabsf(c), 1e-12f);
    }
    float acc = 0.f;
    for (int i=0;i<32;i++){
      float mx = -1e30f;
      for (int j=0;j<32;j++) mx = fmaxf(mx, sn1[i]*sn2[j]);
      float se = 0.f;
      for (int j=0;j<32;j++) se += expf(sn1[i]*sn2[j]-mx);
      acc += sn1[i]*sn2[i] - (mx + logf(se));
    }
    loss_s = -acc/32.f;
  }
  __syncthreads();
  out[t*4+0] = scores[t];
  out[t*4+1] = scores[32+t];
  out[t*4+2] = scores[64+t];
  out[t*4+3] = loss_s;
}

extern "C" void kernel_launch(void* const* d_in, const int* in_sizes, int n_in,
                              void* d_out, int out_size, void* d_ws, size_t ws_size,
                              hipStream_t stream){
  static const int exp_sizes[38] = {
    Nn*INFc, Ec, Ec, Bc*LPc, INFc*Dd,
    9*Dd*Dd, 9*Dd, 9*Dd*Dd, 9*Dd,
    26*Dd, Dd*Dd*3, Dd*Dd*6, Dd*Dd*9, 3*Dd, 3*Dd, 3*Dd,
    Dd*HKc, HKc, Dd*HKc, HKc, 2*HKc, 2, 256, 256,
    256*512, 512, 512*512, 512, 512*128, 128, 128, 1,
    512, 512, 512, 512, 128, 128 };
  if (n_in != 38){ k_sentinel<<<1,128,0,stream>>>((float*)d_out, 2000.f + n_in); return; }
  for (int i=0;i<38;i++){
    if (in_sizes[i] != exp_sizes[i]){
      k_sentinel<<<1,128,0,stream>>>((float*)d_out, 1000.f + i); return;
    }
  }

  const float* node_h=(const float*)d_in[0];
  const int*  esrc  =(const int*)d_in[1];
  const int*  edst  =(const int*)d_in[2];
  const int*  vp    =(const int*)d_in[3];
  const float* W_init=(const float*)d_in[4];
  const float* gcn_W =(const float*)d_in[5];
  const float* gcn_b =(const float*)d_in[6];
  const float* gcn_Wr=(const float*)d_in[7];
  const float* gcn_br=(const float*)d_in[8];
  const float* emb   =(const float*)d_in[9];
  const float* c1w=(const float*)d_in[10];
  const float* c2w=(const float*)d_in[11];
  const float* c3w=(const float*)d_in[12];
  const float* cbv=(const float*)d_in[13];
  const float* bng=(const float*)d_in[14];
  const float* bnb=(const float*)d_in[15];
  const float* Wv =(const float*)d_in[16];
  const float* bvv=(const float*)d_in[17];
  const float* Wq =(const float*)d_in[18];
  const float* bq =(const float*)d_in[19];
  const float* hmat =(const float*)d_in[20];
  const float* hbias=(const float*)d_in[21];
  const float* bang =(const float*)d_in[22];
  const float* banb =(const float*)d_in[23];
  const float* mw1=(const float*)d_in[24]; const float* mb1=(const float*)d_in[25];
  const float* mw2=(const float*)d_in[26]; const float* mb2=(const float*)d_in[27];
  const float* mw3=(const float*)d_in[28]; const float* mb3=(const float*)d_in[29];
  const float* mw4=(const float*)d_in[30]; const float* mb4=(const float*)d_in[31];
  const float* g1=(const float*)d_in[32]; const float* bb1=(const float*)d_in[33];
  const float* g2=(const float*)d_in[34]; const float* bb2=(const float*)d_in[35];
  const float* g3=(const float*)d_in[36]; const float* bb3=(const float*)d_in[37];

  float* ws = (float*)d_ws;
  size_t off = 0;
  auto alloc = [&](size_t n){ float* p = ws + off; off += n; return p; };

  const size_t NDsz = (size_t)Nn*Dd;              // 1,187,840
  const size_t CNNBP = (size_t)Bc*Dd*S1;          // 3,702,784
  const size_t ADJ  = (size_t)Bc*NPGc*NPGc;       // 2,691,200
  const size_t ARENA_MIN = 4*NDsz + ADJ;          // 7,442,560 (covers 2*CNNBP too)

  // smalls
  float* Sq   = alloc((size_t)Bc*HKc);
  float* Sv3  = alloc((size_t)3*Bc*HKc);
  float* fbuf3= alloc((size_t)3*Bc*HKc);
  float* fpool3=alloc((size_t)3*Bc*256);
  float* hh1  = alloc((size_t)96*512);
  float* hh2  = alloc((size_t)96*512);
  float* hh3  = alloc((size_t)96*128);
  float* sc   = alloc(96);
  float* scl1 = alloc(128); float* shf1 = alloc(128);
  float* scl2 = alloc(128); float* shf2 = alloc(128);
  float* scl3 = alloc(128); float* shf3 = alloc(128);
  float* wT1 = alloc((size_t)Dd*Dd*3);
  float* wT2 = alloc((size_t)Dd*Dd*6);
  float* wT3 = alloc((size_t)Dd*Dd*9);
  float* Gq  = alloc((size_t)Bc*HKc*HKc);
  size_t base_floats = off;

  // ---- tier selection on ws_size (constant per run -> graph-capture safe) ----
  // tier qbuf rows per graph = 885 (full), graphs/pass: 32 / 16 / chunked fallback
  const size_t QB32 = (size_t)32*LQ*HKc;   // 21,749,760
  const size_t QB16 = (size_t)16*LQ*HKc;   // 10,874,880
  size_t arenaA = CNNBP + QB32; if (arenaA < ARENA_MIN) arenaA = ARENA_MIN;
  size_t arenaB = CNNBP + QB16; if (arenaB < ARENA_MIN) arenaB = ARENA_MIN;
  int tier;
  size_t arena_sz;
  if (ws_size >= (base_floats + arenaA)*4) { tier = 32; arena_sz = arenaA; }
  else if (ws_size >= (base_floats + arenaB)*4) { tier = 16; arena_sz = arenaB; }
  else { tier = 0; arena_sz = ARENA_MIN; }

  float* arena = alloc(arena_sz);

  // phase views
  float* cnnA = arena;
  float* cnnB = arena + CNNBP;
  float* qbuf = arena + CNNBP;          // q rows (full or chunk window)
  float* A0 = arena;
  float* A1 = arena + NDsz;
  float* A2t= arena + 2*NDsz;
  float* A3 = arena + 3*NDsz;
  float* vbuf = arena + NDsz;           // spans dead A1/A2t/A3 (h0 recomputed per branch)
  float* Adj  = arena + 4*NDsz;

  // ---- conv weight transposes ----
  k_wT<<<(Dd*Dd*3+255)/256,256,0,stream>>>(wT1, c1w, 3);
  k_wT<<<(Dd*Dd*6+255)/256,256,0,stream>>>(wT2, c2w, 6);
  k_wT<<<(Dd*Dd*9+255)/256,256,0,stream>>>(wT3, c3w, 9);

  // ---- ProteinCNN (BN folded into next stage-in) ----
  k_embed<<<dim3((LPc+127)/128, Dd, Bc),128,0,stream>>>(cnnB, vp, emb);
  k_convg2<3><<<dim3(15,Bc),256,0,stream>>>(cnnA, cnnB, wT1, cbv, nullptr, nullptr, 900, 898, 900, S1, 0);
  k_bnc_stats2<<<Dd,256,0,stream>>>(scl1, shf1, cnnA, 898, S1, bng, bnb, 0);
  k_convg2<6><<<dim3(14,Bc),256,0,stream>>>(cnnB, cnnA, wT2, cbv, scl1, shf1, 898, 893, S1, S2, 128);
  k_bnc_stats2<<<Dd,256,0,stream>>>(scl2, shf2, cnnB, 893, S2, bng, bnb, 128);
  k_convg2<9><<<dim3(14,Bc),256,0,stream>>>(cnnA, cnnB, wT3, cbv, scl2, shf2, 893, 885, S2, S3, 256);
  k_bnc_stats2<<<Dd,256,0,stream>>>(scl3, shf3, cnnA, 885, S3, bng, bnb, 256);

  // ---- q branch -> Gq (single-shot when workspace permits) ----
  if (tier > 0){
    for (int bbase = 0; bbase < Bc; bbase += tier){
      k_qgemmF<<<dim3(12,(LQ+127)/128,tier),256,0,stream>>>(qbuf, cnnA, Wq, bq, scl3, shf3, bbase, 0, LQ, LQ);
      k_colsumF<<<dim3(3,tier),256,0,stream>>>(Sq, qbuf, bbase, LQ, LQ, 1);
      k_gramF<<<dim3(21,tier),256,0,stream>>>(Gq, qbuf, bbase, LQ, LQ, 1);
    }
  } else {
    for (int t0c = 0, ci = 0; t0c < LQ; t0c += CHT, ci++){
      int Tc = LQ - t0c; if (Tc > CHT) Tc = CHT;
      k_qgemmF<<<dim3(12,1,Bc),256,0,stream>>>(qbuf, cnnA, Wq, bq, scl3, shf3, 0, t0c, Tc, CHT);
      k_colsumF<<<dim3(3,Bc),256,0,stream>>>(Sq, qbuf, 0, Tc, CHT, ci==0);
      k_gramF<<<dim3(21,Bc),256,0,stream>>>(Gq, qbuf, 0, Tc, CHT, ci==0);
    }
  }

  // ---- dense adjacency ----
  hipMemsetAsync(Adj, 0, ADJ*sizeof(float), stream);
  k_build_adj<<<(Ec+255)/256,256,0,stream>>>(Adj, esrc, edst);

  hipMemsetAsync(fbuf3, 0, (size_t)3*Bc*HKc*sizeof(float), stream);

  // ---- three GCN branches + Gram-fused BAN (h0 recomputed per branch) ----
  for (int g=0; g<3; g++){
    k_h0<<<Nn,Dd,0,stream>>>(A1, node_h, W_init);
    { int wo=g*3+0;
      k_gcn_fused<<<dim3(37,Bc),128,0,stream>>>(A3, Adj, A1, gcn_W+(size_t)wo*Dd*Dd, gcn_b+(size_t)wo*Dd,
                                                gcn_Wr+(size_t)wo*Dd*Dd, gcn_br+(size_t)wo*Dd); }
    { int wo=g*3+1;
      k_gcn_fused<<<dim3(37,Bc),128,0,stream>>>(A2t, Adj, A3, gcn_W+(size_t)wo*Dd*Dd, gcn_b+(size_t)wo*Dd,
                                                gcn_Wr+(size_t)wo*Dd*Dd, gcn_br+(size_t)wo*Dd); }
    { int wo=g*3+2;
      k_gcn_fused<<<dim3(37,Bc),128,0,stream>>>(A0, Adj, A2t, gcn_W+(size_t)wo*Dd*Dd, gcn_b+(size_t)wo*Dd,
                                                gcn_Wr+(size_t)wo*Dd*Dd, gcn_br+(size_t)wo*Dd); }

    for (int p=0; p<2; p++){
      int bbase = p*16;
      k_vgemm8<<<dim3(3,(16*NPGc)/8),256,0,stream>>>(vbuf, A0, Wv, bvv, bbase*NPGc);
      k_colsum_v<<<dim3(3,16),256,0,stream>>>(Sv3 + (size_t)g*Bc*HKc, vbuf, bbase);
      k_gramf2<<<dim3(21,1,16),256,0,stream>>>(fbuf3 + (size_t)g*Bc*HKc, vbuf, Gq, hmat, bbase);
    }
  }

  // ---- batched tail over 3 views (96 rows) ----
  k_pool3<<<(3*Bc*256+255)/256,256,0,stream>>>(fpool3, fbuf3, Sv3, Sq, hbias);
  k_bnfeat3<<<dim3(256,3),32,0,stream>>>(fpool3, fpool3, bang, banb, 256);
  k_mlp<<<dim3(2,96),256,0,stream>>>(hh1, fpool3, mw1, mb1, 256, 512, 1);
  k_bnfeat3<<<dim3(512,3),32,0,stream>>>(hh1, hh1, g1, bb1, 512);
  k_mlp<<<dim3(2,96),256,0,stream>>>(hh2, hh1, mw2, mb2, 512, 512, 1);
  k_bnfeat3<<<dim3(512,3),32,0,stream>>>(hh2, hh2, g2, bb2, 512);
  k_mlp<<<dim3(1,96),256,0,stream>>>(hh3, hh2, mw3, mb3, 512, 128, 1);
  k_bnfeat3<<<dim3(128,3),32,0,stream>>>(hh3, hh3, g3, bb3, 128);
  k_score96<<<1,96,0,stream>>>(sc, hh3, mw4, mb4);
  k_out<<<1,32,0,stream>>>((float*)d_out, sc);
}

// Round 15
// 2802.288 us; speedup vs baseline: 1.2305x; 1.1696x over previous
//
#include <hip/hip_runtime.h>
#include <hip/hip_bf16.h>

#define Bc 32
#define NPGc 290
#define Nn 9280
#define Ec 74240
#define LPc 900
#define INFc 75
#define Dd 128
#define HKc 768
#define LQ 885
#define S1 904
#define S2 896
#define S3 888
#define LP128 132   // padded LDS stride for 128-wide tiles

__global__ void k_sentinel(float* out, float val){
  int t = threadIdx.x;
  if (t < 128) out[t] = val;
}

// ---------------- GCN ----------------
__global__ void k_h0(float* __restrict__ h0, const float* __restrict__ nh, const float* __restrict__ Wi){
  int n = blockIdx.x, j = threadIdx.x;
  __shared__ float arow[INFc];
  if (j < INFc) arow[j] = nh[(size_t)n*INFc + j];
  __syncthreads();
  float s = 0.f;
  #pragma unroll 5
  for (int k=0;k<INFc;k++) s += arow[k]*Wi[(size_t)k*Dd + j];
  h0[(size_t)n*Dd + j] = s;
}

__global__ void k_build_adj(float* __restrict__ A, const int* __restrict__ src, const int* __restrict__ dst){
  int e = blockIdx.x*blockDim.x + threadIdx.x;
  if (e >= Ec) return;
  int s = src[e], d = dst[e];
  int b = d / NPGc;
  int dl = d - b*NPGc, sl = s - b*NPGc;
  atomicAdd(&A[((size_t)b*NPGc + dl)*NPGc + sl], 1.f);
}

__global__ void k_gcn_fused(float* __restrict__ out, const float* __restrict__ A, const float* __restrict__ h,
                            const float* __restrict__ W, const float* __restrict__ bvec,
                            const float* __restrict__ Wr, const float* __restrict__ br){
  int b = blockIdx.y;
  int i0 = blockIdx.x*8;
  int j = threadIdx.x;  // 128
  __shared__ float arow[8][NPGc];
  __shared__ float ar[8][Dd], hr[8][Dd];
  for (int idx=j; idx<8*NPGc; idx+=128){
    int r=idx/NPGc, c=idx-r*NPGc;
    arow[r][c] = (i0+r<NPGc) ? A[((size_t)b*NPGc+i0+r)*NPGc+c] : 0.f;
  }
  for (int idx=j; idx<8*Dd; idx+=128){
    int r=idx>>7, k=idx&127;
    hr[r][k] = (i0+r<NPGc) ? h[((size_t)b*NPGc+i0+r)*Dd+k] : 0.f;
  }
  __syncthreads();
  float acc[8]={};
  const float* hb = h + (size_t)b*NPGc*Dd + j;
  for (int c=0;c<NPGc;c++){
    float hv = hb[(size_t)c*Dd];
    #pragma unroll
    for (int r=0;r<8;r++) acc[r] += arow[r][c]*hv;
  }
  #pragma unroll
  for (int r=0;r<8;r++) ar[r][j] = acc[r];
  __syncthreads();
  float s1[8], s2[8];
  float bj = bvec[j], brj = br[j];
  #pragma unroll
  for (int r=0;r<8;r++){ s1[r]=bj; s2[r]=brj; }
  for (int k=0;k<Dd;k++){
    float wk = W[(size_t)k*Dd+j], wrk = Wr[(size_t)k*Dd+j];
    #pragma unroll
    for (int r=0;r<8;r++){ s1[r] += ar[r][k]*wk; s2[r] += hr[r][k]*wrk; }
  }
  int nr = NPGc - i0; if (nr > 8) nr = 8;
  for (int r=0;r<nr;r++)
    out[((size_t)b*NPGc+i0+r)*Dd + j] = fmaxf(s1[r],0.f) + fmaxf(s2[r],0.f);
}

// ---------------- ProteinCNN ----------------
__global__ void k_embed(float* __restrict__ x, const int* __restrict__ vp, const float* __restrict__ emb){
  int t = blockIdx.x*blockDim.x + threadIdx.x;
  int d = blockIdx.y, b = blockIdx.z;
  if (t >= LPc) return;
  int tok = vp[b*LPc + t];
  x[((size_t)b*Dd + d)*LPc + t] = emb[(size_t)tok*Dd + d];
}

__global__ void k_wT(float* __restrict__ wT, const float* __restrict__ w, int KW){
  int idx = blockIdx.x*256 + threadIdx.x;
  int tot = Dd*Dd*KW;
  if (idx >= tot) return;
  int o = idx & 127; int rest = idx >> 7;
  wT[(size_t)rest*Dd + o] = w[((size_t)o*Dd + rest/KW)*KW + (rest % KW)];
}

// conv GEMM: M=128(o) x N=64(t), 8x4/thread, padded As -> no conflicts (r14, passed)
template<int KW>
__global__ void k_convg2(float* __restrict__ y, const float* __restrict__ x, const float* __restrict__ wT,
                         const float* __restrict__ cb, const float* __restrict__ scale,
                         const float* __restrict__ shift, int Lin, int Lout, int XS, int YS, int cbo){
  int b = blockIdx.y;
  int t0 = blockIdx.x*64;
  __shared__ float As[16][LP128], Bs[16][64];
  int tid=threadIdx.x, tx=tid&15, ty=tid>>4;
  int ldr=tid>>4;
  int ldc8=(tid&15)*8, ldc4=(tid&15)*4;
  float acc[8][4]={};
  const int KT = Dd*KW;
  for (int k0=0; k0<KT; k0+=16){
    *(float4*)&As[ldr][ldc8]   = *(const float4*)(wT + (size_t)(k0+ldr)*Dd + ldc8);
    *(float4*)&As[ldr][ldc8+4] = *(const float4*)(wT + (size_t)(k0+ldr)*Dd + ldc8+4);
    int kr = k0+ldr; int i = kr/KW, k = kr - i*KW;
    float sc_ = scale ? scale[i] : 1.f;
    float sh_ = shift ? shift[i] : 0.f;
    const float* xr = x + ((size_t)b*Dd + i)*XS + t0 + k + ldc4;
    int tb = t0 + k + ldc4;
    Bs[ldr][ldc4+0] = (tb+0 < Lin) ? xr[0]*sc_+sh_ : 0.f;
    Bs[ldr][ldc4+1] = (tb+1 < Lin) ? xr[1]*sc_+sh_ : 0.f;
    Bs[ldr][ldc4+2] = (tb+2 < Lin) ? xr[2]*sc_+sh_ : 0.f;
    Bs[ldr][ldc4+3] = (tb+3 < Lin) ? xr[3]*sc_+sh_ : 0.f;
    __syncthreads();
    #pragma unroll
    for (int kk=0;kk<16;kk++){
      float a[8], bb[4];
      *(float4*)&a[0] = *(const float4*)&As[kk][ty*4];
      *(float4*)&a[4] = *(const float4*)&As[kk][64+ty*4];
      *(float4*)bb = *(const float4*)&Bs[kk][tx*4];
      #pragma unroll
      for (int i2=0;i2<8;i2++)
        #pragma unroll
        for (int j2=0;j2<4;j2++) acc[i2][j2] += a[i2]*bb[j2];
    }
    __syncthreads();
  }
  int t = t0 + tx*4;
  #pragma unroll
  for (int i2=0;i2<8;i2++){
    int o = (i2<4) ? ty*4+i2 : 64+ty*4+(i2-4);
    float bias = cb[cbo+o];
    float* yp = y + ((size_t)b*Dd+o)*YS + t;
    if (t+3 < Lout){
      float4 v;
      v.x=fmaxf(acc[i2][0]+bias,0.f); v.y=fmaxf(acc[i2][1]+bias,0.f);
      v.z=fmaxf(acc[i2][2]+bias,0.f); v.w=fmaxf(acc[i2][3]+bias,0.f);
      *(float4*)yp = v;
    } else {
      for (int j2=0;j2<4;j2++) if (t+j2 < Lout) yp[j2] = fmaxf(acc[i2][j2]+bias,0.f);
    }
  }
}

// stats -> scale/shift (BN fold)
__global__ void k_bnc_stats2(float* __restrict__ scale, float* __restrict__ shift,
                             const float* __restrict__ y, int Lout, int YS,
                             const float* __restrict__ g, const float* __restrict__ bb, int go){
  int c = blockIdx.x;
  float s=0.f, ss=0.f;
  int cnt = Bc*Lout;
  for (int i = threadIdx.x; i < cnt; i += blockDim.x){
    int b = i / Lout, t = i - b*Lout;
    float v = y[((size_t)b*Dd+c)*YS + t];
    s += v; ss += v*v;
  }
  __shared__ float rs[256], rss[256];
  rs[threadIdx.x]=s; rss[threadIdx.x]=ss; __syncthreads();
  for (int st=128; st>0; st>>=1){
    if (threadIdx.x<st){ rs[threadIdx.x]+=rs[threadIdx.x+st]; rss[threadIdx.x]+=rss[threadIdx.x+st]; }
    __syncthreads();
  }
  if (threadIdx.x==0){
    float m = rs[0]/cnt; float v = rss[0]/cnt - m*m; if (v<0.f) v=0.f;
    float r = rsqrtf(v+1e-5f);
    float scl = r*g[go+c];
    scale[c] = scl;
    shift[c] = bb[go+c] - m*scl;
  }
}

// ---------------- BAN Gram path: 64x64 tiles, 4x4/thread (no-spill, proven r11 shape) ----------------
// q GEMM full length for 4-graph group: M=t(64) x N=j(64), BN fused
__global__ void k_qgemm_tile(float* __restrict__ qc, const float* __restrict__ x,
                             const float* __restrict__ W, const float* __restrict__ bias,
                             const float* __restrict__ scale, const float* __restrict__ shift,
                             int gbase){
  int bl = blockIdx.z, b = gbase + bl;
  int m0 = blockIdx.y*64;
  int n0 = blockIdx.x*64;
  __shared__ float As[16][64], Bs[16][64];
  int tid = threadIdx.x;
  int tx = tid & 15, ty = tid >> 4;
  int ldr = tid >> 4, ldc = (tid & 15)*4;
  float acc[4][4] = {};
  for (int k0 = 0; k0 < Dd; k0 += 16){
    int d = k0 + ldr;
    float sc_ = scale[d], sh_ = shift[d];
    const float* xrow = x + ((size_t)b*Dd + d)*S3 + m0 + ldc;
    int mb = m0 + ldc;
    As[ldr][ldc+0] = (mb+0 < LQ) ? xrow[0]*sc_+sh_ : 0.f;
    As[ldr][ldc+1] = (mb+1 < LQ) ? xrow[1]*sc_+sh_ : 0.f;
    As[ldr][ldc+2] = (mb+2 < LQ) ? xrow[2]*sc_+sh_ : 0.f;
    As[ldr][ldc+3] = (mb+3 < LQ) ? xrow[3]*sc_+sh_ : 0.f;
    *(float4*)&Bs[ldr][ldc] = *(const float4*)(W + (size_t)d*HKc + n0 + ldc);
    __syncthreads();
    #pragma unroll
    for (int kk=0; kk<16; kk++){
      float a[4], bb[4];
      *(float4*)a  = *(const float4*)&As[kk][ty*4];
      *(float4*)bb = *(const float4*)&Bs[kk][tx*4];
      #pragma unroll
      for (int i=0;i<4;i++)
        #pragma unroll
        for (int j=0;j<4;j++) acc[i][j] += a[i]*bb[j];
    }
    __syncthreads();
  }
  #pragma unroll
  for (int i=0;i<4;i++){
    int m = m0 + ty*4 + i;
    if (m >= LQ) continue;
    int n = n0 + tx*4;
    float4 b4 = *(const float4*)(bias + n);
    float4 o;
    o.x = fmaxf(acc[i][0] + b4.x, 0.f);
    o.y = fmaxf(acc[i][1] + b4.y, 0.f);
    o.z = fmaxf(acc[i][2] + b4.z, 0.f);
    o.w = fmaxf(acc[i][3] + b4.w, 0.f);
    *(float4*)(qc + ((size_t)bl*LQ + m)*HKc + n) = o;
  }
}

__global__ void k_colsum_q(float* __restrict__ S, const float* __restrict__ X, int gbase){
  int j = blockIdx.x*256 + threadIdx.x;
  int bl = blockIdx.y;
  if (j >= HKc) return;
  const float* p = X + (size_t)bl*LQ*HKc + j;
  float s=0.f;
  for (int t=0;t<LQ;t++) s += p[(size_t)t*HKc];
  S[(gbase+bl)*HKc + j] = s;
}

// Gq upper-triangle 64x64 tiles (78), 4x4/thread, full-K single-shot store
__global__ void k_gram_sym(float* __restrict__ G, const float* __restrict__ X, int gbase){
  int bl = blockIdx.y, bg = gbase + bl;
  int tl = blockIdx.x; int ti = 0;
  while (tl >= 12-ti){ tl -= 12-ti; ti++; }
  int tj = ti + tl;
  int r0 = ti*64, c0 = tj*64;
  const float* Xb = X + (size_t)bl*LQ*HKc;
  float* Gb = G + (size_t)bg*HKc*HKc;
  __shared__ float As[16][64], Bs[16][64];
  int tid = threadIdx.x;
  int tx = tid & 15, ty = tid >> 4;
  int ldr = tid >> 4, ldc = (tid & 15)*4;
  float acc[4][4] = {};
  for (int t0=0; t0<LQ; t0+=16){
    float4 av = make_float4(0.f,0.f,0.f,0.f), bv4 = make_float4(0.f,0.f,0.f,0.f);
    if (t0+ldr < LQ){
      const float* row = Xb + (size_t)(t0+ldr)*HKc;
      av  = *(const float4*)(row + r0 + ldc);
      bv4 = *(const float4*)(row + c0 + ldc);
    }
    *(float4*)&As[ldr][ldc] = av;
    *(float4*)&Bs[ldr][ldc] = bv4;
    __syncthreads();
    #pragma unroll
    for (int tt=0; tt<16; tt++){
      float a[4], bb[4];
      *(float4*)a  = *(const float4*)&As[tt][ty*4];
      *(float4*)bb = *(const float4*)&Bs[tt][tx*4];
      #pragma unroll
      for (int i=0;i<4;i++)
        #pragma unroll
        for (int j=0;j<4;j++) acc[i][j] += a[i]*bb[j];
    }
    __syncthreads();
  }
  for (int i=0;i<4;i++){
    int r = r0 + ty*4 + i;
    *(float4*)(Gb + (size_t)r*HKc + c0 + tx*4) =
      make_float4(acc[i][0],acc[i][1],acc[i][2],acc[i][3]);
  }
}

__global__ void k_vgemm8(float* __restrict__ v, const float* __restrict__ vd,
                         const float* __restrict__ W, const float* __restrict__ bias, int rbase){
  int j = blockIdx.x*256 + threadIdx.x;
  int r0 = blockIdx.y*8;
  __shared__ float xr[8][Dd];
  for (int idx=threadIdx.x; idx<8*Dd; idx+=256){
    int r = idx>>7, k = idx&127;
    xr[r][k] = vd[(size_t)(rbase + r0 + r)*Dd + k];
  }
  __syncthreads();
  float acc[8];
  float bj = bias[j];
  #pragma unroll
  for (int r=0;r<8;r++) acc[r]=bj;
  for (int k=0;k<Dd;k++){
    float wk = W[(size_t)k*HKc+j];
    #pragma unroll
    for (int r=0;r<8;r++) acc[r] += xr[r][k]*wk;
  }
  #pragma unroll
  for (int r=0;r<8;r++)
    v[(size_t)(r0+r)*HKc + j] = fmaxf(acc[r],0.f);
}

__global__ void k_colsum_v(float* __restrict__ S, const float* __restrict__ X, int bbase){
  int j = blockIdx.x*blockDim.x + threadIdx.x;
  int bl = blockIdx.y;
  if (j >= HKc) return;
  const float* p = X + (size_t)bl*NPGc*HKc + j;
  float s=0.f;
  for (int t=0;t<NPGc;t++) s += p[(size_t)t*HKc];
  S[(bbase+bl)*HKc + j] = s;
}

// gramf over upper-triangle 64-tiles (78); off-diag contributes both row/col (r11 proven)
__global__ void k_gramf_sym(float* __restrict__ f, const float* __restrict__ V,
                            const float* __restrict__ Gq_, const float* __restrict__ hm, int bbase){
  int bl = blockIdx.z, bg = bbase + bl;
  int tl = blockIdx.x; int ti = 0;
  while (tl >= 12-ti){ tl -= 12-ti; ti++; }
  int tj = ti + tl;
  int r0 = ti*64, c0 = tj*64;
  int offdiag = (ti != tj);
  const float* Vb = V + (size_t)bl*NPGc*HKc;
  __shared__ float As[16][64], Bs[16][64];
  __shared__ float wc[64], wr[64];
  int tid = threadIdx.x;
  int tx = tid & 15, ty = tid >> 4;
  int ldr = tid >> 4, ldc = (tid & 15)*4;
  if (tid < 64) wc[tid] = hm[c0+tid] + hm[HKc + c0 + tid];
  else if (tid < 128) wr[tid-64] = hm[r0+tid-64] + hm[HKc + r0 + tid-64];
  float acc[4][4] = {};
  for (int t0=0; t0<NPGc; t0+=16){
    float4 av = make_float4(0.f,0.f,0.f,0.f), bv4 = make_float4(0.f,0.f,0.f,0.f);
    if (t0+ldr < NPGc){
      const float* row = Vb + (size_t)(t0+ldr)*HKc;
      av  = *(const float4*)(row + r0 + ldc);
      bv4 = *(const float4*)(row + c0 + ldc);
    }
    *(float4*)&As[ldr][ldc] = av;
    *(float4*)&Bs[ldr][ldc] = bv4;
    __syncthreads();
    #pragma unroll
    for (int tt=0; tt<16; tt++){
      float a[4], bb[4];
      *(float4*)a  = *(const float4*)&As[tt][ty*4];
      *(float4*)bb = *(const float4*)&Bs[tt][tx*4];
      #pragma unroll
      for (int i=0;i<4;i++)
        #pragma unroll
        for (int j=0;j<4;j++) acc[i][j] += a[i]*bb[j];
    }
    __syncthreads();
  }
  const float* gqb = Gq_ + (size_t)bg*HKc*HKc;
  float w0 = wc[tx*4+0], w1 = wc[tx*4+1], w2 = wc[tx*4+2], w3 = wc[tx*4+3];
  float colp[4] = {0.f,0.f,0.f,0.f};
  #pragma unroll
  for (int i=0;i<4;i++){
    int r = r0 + ty*4 + i;
    const float4 g4 = *(const float4*)(gqb + (size_t)r*HKc + c0 + tx*4);
    float s = acc[i][0]*w0*g4.x + acc[i][1]*w1*g4.y
            + acc[i][2]*w2*g4.z + acc[i][3]*w3*g4.w;
    s += __shfl_xor(s, 1); s += __shfl_xor(s, 2);
    s += __shfl_xor(s, 4); s += __shfl_xor(s, 8);
    if (tx==0) atomicAdd(&f[bg*HKc + r], s);
    if (offdiag){
      float wri = wr[ty*4+i];
      colp[0] += acc[i][0]*wri*g4.x;
      colp[1] += acc[i][1]*wri*g4.y;
      colp[2] += acc[i][2]*wri*g4.z;
      colp[3] += acc[i][3]*wri*g4.w;
    }
  }
  if (offdiag){
    #pragma unroll
    for (int j=0;j<4;j++){
      colp[j] += __shfl_xor(colp[j], 16);
      colp[j] += __shfl_xor(colp[j], 32);
    }
    if ((tid & 48) == 0){
      #pragma unroll
      for (int j=0;j<4;j++)
        atomicAdd(&f[bg*HKc + c0 + tx*4 + j], colp[j]);
    }
  }
}

// batched pool over 3 views
__global__ void k_pool3(float* __restrict__ fp, const float* __restrict__ f3,
                        const float* __restrict__ Sv3, const float* __restrict__ Sq,
                        const float* __restrict__ hb){
  int idx = blockIdx.x*256 + threadIdx.x;
  if (idx >= 3*Bc*256) return;
  int v = idx >> 13;
  int rem = idx & 8191;
  int b = rem >> 8, c = rem & 255;
  const float* f = f3 + (size_t)v*Bc*HKc;
  const float* Sv = Sv3 + (size_t)v*Bc*HKc;
  float hbs = hb[0] + hb[1];
  float s = 0.f;
  #pragma unroll
  for (int r=0;r<3;r++){
    int k = c*3 + r;
    s += f[b*HKc + k] + hbs*Sv[b*HKc + k]*Sq[b*HKc + k];
  }
  fp[idx] = s;
}

// batched BN over 3 views
__global__ void k_bnfeat3(float* __restrict__ y, const float* __restrict__ x, const float* __restrict__ g,
                          const float* __restrict__ bb, int C){
  int c = blockIdx.x; int v = blockIdx.y; int b = threadIdx.x;
  __shared__ float buf[32];
  __shared__ float mv[2];
  int row = v*32 + b;
  float val = x[(size_t)row*C + c];
  buf[b] = val;
  __syncthreads();
  if (b == 0){
    float s = 0.f;
    for (int i=0;i<32;i++) s += buf[i];
    float m = s/32.f;
    float vs = 0.f;
    for (int i=0;i<32;i++){ float d = buf[i]-m; vs += d*d; }
    mv[0] = m; mv[1] = vs/32.f;
  }
  __syncthreads();
  y[(size_t)row*C + c] = (val - mv[0])*rsqrtf(mv[1]+1e-5f)*g[c] + bb[c];
}

__global__ void k_mlp(float* __restrict__ out, const float* __restrict__ in, const float* __restrict__ W,
                      const float* __restrict__ bias, int K, int Nc, int doRelu){
  int b = blockIdx.y;   // 96 rows
  int j = blockIdx.x*blockDim.x + threadIdx.x;
  __shared__ float xr[512];
  for (int k=threadIdx.x; k<K; k+=blockDim.x) xr[k] = in[(size_t)b*K+k];
  __syncthreads();
  if (j >= Nc) return;
  float s = bias[j];
  for (int k=0;k<K;k++) s += xr[k]*W[(size_t)k*Nc + j];
  if (doRelu) s = fmaxf(s, 0.f);
  out[(size_t)b*Nc + j] = s;
}

__global__ void k_score96(float* __restrict__ sc, const float* __restrict__ h, const float* __restrict__ w,
                          const float* __restrict__ bb){
  int b = threadIdx.x; if (b>=96) return;
  float s = bb[0];
  for (int k=0;k<Dd;k++) s += h[(size_t)b*Dd+k]*w[k];
  sc[b] = s;
}

__global__ void k_out(float* __restrict__ out, const float* __restrict__ scores){
  int t = threadIdx.x;
  __shared__ float loss_s;
  if (t == 0){
    float sn1[32], sn2[32];
    for (int i=0;i<32;i++){
      float a = scores[32+i]; sn1[i] = a / fmaxf(fabsf(a), 1e-12f);
      float c = scores[64+i]; sn2[i] = c / fmaxf(fabsf(c), 1e-12f);
    }
    float acc = 0.f;
    for (int i=0;i<32;i++){
      float mx = -1e30f;
      for (int j=0;j<32;j++) mx = fmaxf(mx, sn1[i]*sn2[j]);
      float se = 0.f;
      for (int j=0;j<32;j++) se += expf(sn1[i]*sn2[j]-mx);
      acc += sn1[i]*sn2[i] - (mx + logf(se));
    }
    loss_s = -acc/32.f;
  }
  __syncthreads();
  out[t*4+0] = scores[t];
  out[t*4+1] = scores[32+t];
  out[t*4+2] = scores[64+t];
  out[t*4+3] = loss_s;
}

extern "C" void kernel_launch(void* const* d_in, const int* in_sizes, int n_in,
                              void* d_out, int out_size, void* d_ws, size_t ws_size,
                              hipStream_t stream){
  static const int exp_sizes[38] = {
    Nn*INFc, Ec, Ec, Bc*LPc, INFc*Dd,
    9*Dd*Dd, 9*Dd, 9*Dd*Dd, 9*Dd,
    26*Dd, Dd*Dd*3, Dd*Dd*6, Dd*Dd*9, 3*Dd, 3*Dd, 3*Dd,
    Dd*HKc, HKc, Dd*HKc, HKc, 2*HKc, 2, 256, 256,
    256*512, 512, 512*512, 512, 512*128, 128, 128, 1,
    512, 512, 512, 512, 128, 128 };
  if (n_in != 38){ k_sentinel<<<1,128,0,stream>>>((float*)d_out, 2000.f + n_in); return; }
  for (int i=0;i<38;i++){
    if (in_sizes[i] != exp_sizes[i]){
      k_sentinel<<<1,128,0,stream>>>((float*)d_out, 1000.f + i); return;
    }
  }

  const float* node_h=(const float*)d_in[0];
  const int*  esrc  =(const int*)d_in[1];
  const int*  edst  =(const int*)d_in[2];
  const int*  vp    =(const int*)d_in[3];
  const float* W_init=(const float*)d_in[4];
  const float* gcn_W =(const float*)d_in[5];
  const float* gcn_b =(const float*)d_in[6];
  const float* gcn_Wr=(const float*)d_in[7];
  const float* gcn_br=(const float*)d_in[8];
  const float* emb   =(const float*)d_in[9];
  const float* c1w=(const float*)d_in[10];
  const float* c2w=(const float*)d_in[11];
  const float* c3w=(const float*)d_in[12];
  const float* cbv=(const float*)d_in[13];
  const float* bng=(const float*)d_in[14];
  const float* bnb=(const float*)d_in[15];
  const float* Wv =(const float*)d_in[16];
  const float* bvv=(const float*)d_in[17];
  const float* Wq =(const float*)d_in[18];
  const float* bq =(const float*)d_in[19];
  const float* hmat =(const float*)d_in[20];
  const float* hbias=(const float*)d_in[21];
  const float* bang =(const float*)d_in[22];
  const float* banb =(const float*)d_in[23];
  const float* mw1=(const float*)d_in[24]; const float* mb1=(const float*)d_in[25];
  const float* mw2=(const float*)d_in[26]; const float* mb2=(const float*)d_in[27];
  const float* mw3=(const float*)d_in[28]; const float* mb3=(const float*)d_in[29];
  const float* mw4=(const float*)d_in[30]; const float* mb4=(const float*)d_in[31];
  const float* g1=(const float*)d_in[32]; const float* bb1=(const float*)d_in[33];
  const float* g2=(const float*)d_in[34]; const float* bb2=(const float*)d_in[35];
  const float* g3=(const float*)d_in[36]; const float* bb3=(const float*)d_in[37];

  float* ws = (float*)d_ws;
  size_t off = 0;
  auto alloc = [&](size_t n){ float* p = ws + off; off += n; return p; };

  const size_t NDsz = (size_t)Nn*Dd;              // 1,187,840
  const size_t CNNBP = (size_t)Bc*Dd*S1;          // 3,702,784
  const size_t ADJ  = (size_t)Bc*NPGc*NPGc;       // 2,691,200
  const size_t QB4  = (size_t)4*LQ*HKc;           // 2,718,720 (4-graph full-length q)
  size_t ARENA = 4*NDsz + ADJ;                    // 7,442,560
  if (ARENA < CNNBP + QB4) ARENA = CNNBP + QB4;   // 6,421,504 < above -> unchanged

  // smalls
  float* Sq   = alloc((size_t)Bc*HKc);
  float* Sv3  = alloc((size_t)3*Bc*HKc);
  float* fbuf3= alloc((size_t)3*Bc*HKc);
  float* fpool3=alloc((size_t)3*Bc*256);
  float* hh1  = alloc((size_t)96*512);
  float* hh2  = alloc((size_t)96*512);
  float* hh3  = alloc((size_t)96*128);
  float* sc   = alloc(96);
  float* scl1 = alloc(128); float* shf1 = alloc(128);
  float* scl2 = alloc(128); float* shf2 = alloc(128);
  float* scl3 = alloc(128); float* shf3 = alloc(128);
  float* wT1 = alloc((size_t)Dd*Dd*3);
  float* wT2 = alloc((size_t)Dd*Dd*6);
  float* wT3 = alloc((size_t)Dd*Dd*9);
  float* Gq  = alloc((size_t)Bc*HKc*HKc);
  float* arena = alloc(ARENA);
  // total ≈ 26.9M floats ≈ 107.7 MiB (same as r14 tier-0, proven safe)

  // phase views
  float* cnnA = arena;
  float* cnnB = arena + CNNBP;
  float* qbuf = arena + CNNBP;          // 4-graph full-length q (2.72M < ARENA-CNNBP)
  float* A0 = arena;
  float* A1 = arena + NDsz;
  float* A2t= arena + 2*NDsz;
  float* A3 = arena + 3*NDsz;
  float* vbuf = arena + NDsz;           // spans dead A1/A2t/A3 (h0 recomputed per branch)
  float* Adj  = arena + 4*NDsz;

  // ---- conv weight transposes ----
  k_wT<<<(Dd*Dd*3+255)/256,256,0,stream>>>(wT1, c1w, 3);
  k_wT<<<(Dd*Dd*6+255)/256,256,0,stream>>>(wT2, c2w, 6);
  k_wT<<<(Dd*Dd*9+255)/256,256,0,stream>>>(wT3, c3w, 9);

  // ---- ProteinCNN (BN folded into next stage-in) ----
  k_embed<<<dim3((LPc+127)/128, Dd, Bc),128,0,stream>>>(cnnB, vp, emb);
  k_convg2<3><<<dim3(15,Bc),256,0,stream>>>(cnnA, cnnB, wT1, cbv, nullptr, nullptr, 900, 898, 900, S1, 0);
  k_bnc_stats2<<<Dd,256,0,stream>>>(scl1, shf1, cnnA, 898, S1, bng, bnb, 0);
  k_convg2<6><<<dim3(14,Bc),256,0,stream>>>(cnnB, cnnA, wT2, cbv, scl1, shf1, 898, 893, S1, S2, 128);
  k_bnc_stats2<<<Dd,256,0,stream>>>(scl2, shf2, cnnB, 893, S2, bng, bnb, 128);
  k_convg2<9><<<dim3(14,Bc),256,0,stream>>>(cnnA, cnnB, wT3, cbv, scl2, shf2, 893, 885, S2, S3, 256);
  k_bnc_stats2<<<Dd,256,0,stream>>>(scl3, shf3, cnnA, 885, S3, bng, bnb, 256);

  // ---- q branch: 8 passes of 4 graphs, full-K single-shot Gq (no RMW) ----
  for (int gb = 0; gb < Bc; gb += 4){
    k_qgemm_tile<<<dim3(12,(LQ+63)/64,4),256,0,stream>>>(qbuf, cnnA, Wq, bq, scl3, shf3, gb);
    k_colsum_q<<<dim3(3,4),256,0,stream>>>(Sq, qbuf, gb);
    k_gram_sym<<<dim3(78,4),256,0,stream>>>(Gq, qbuf, gb);
  }

  // ---- dense adjacency ----
  hipMemsetAsync(Adj, 0, ADJ*sizeof(float), stream);
  k_build_adj<<<(Ec+255)/256,256,0,stream>>>(Adj, esrc, edst);

  hipMemsetAsync(fbuf3, 0, (size_t)3*Bc*HKc*sizeof(float), stream);

  // ---- three GCN branches + Gram-fused BAN (h0 recomputed per branch) ----
  for (int g=0; g<3; g++){
    k_h0<<<Nn,Dd,0,stream>>>(A1, node_h, W_init);
    { int wo=g*3+0;
      k_gcn_fused<<<dim3(37,Bc),128,0,stream>>>(A3, Adj, A1, gcn_W+(size_t)wo*Dd*Dd, gcn_b+(size_t)wo*Dd,
                                                gcn_Wr+(size_t)wo*Dd*Dd, gcn_br+(size_t)wo*Dd); }
    { int wo=g*3+1;
      k_gcn_fused<<<dim3(37,Bc),128,0,stream>>>(A2t, Adj, A3, gcn_W+(size_t)wo*Dd*Dd, gcn_b+(size_t)wo*Dd,
                                                gcn_Wr+(size_t)wo*Dd*Dd, gcn_br+(size_t)wo*Dd); }
    { int wo=g*3+2;
      k_gcn_fused<<<dim3(37,Bc),128,0,stream>>>(A0, Adj, A2t, gcn_W+(size_t)wo*Dd*Dd, gcn_b+(size_t)wo*Dd,
                                                gcn_Wr+(size_t)wo*Dd*Dd, gcn_br+(size_t)wo*Dd); }

    for (int p=0; p<2; p++){
      int bbase = p*16;
      k_vgemm8<<<dim3(3,(16*NPGc)/8),256,0,stream>>>(vbuf, A0, Wv, bvv, bbase*NPGc);
      k_colsum_v<<<dim3(3,16),256,0,stream>>>(Sv3 + (size_t)g*Bc*HKc, vbuf, bbase);
      k_gramf_sym<<<dim3(78,1,16),256,0,stream>>>(fbuf3 + (size_t)g*Bc*HKc, vbuf, Gq, hmat, bbase);
    }
  }

  // ---- batched tail over 3 views (96 rows) ----
  k_pool3<<<(3*Bc*256+255)/256,256,0,stream>>>(fpool3, fbuf3, Sv3, Sq, hbias);
  k_bnfeat3<<<dim3(256,3),32,0,stream>>>(fpool3, fpool3, bang, banb, 256);
  k_mlp<<<dim3(2,96),256,0,stream>>>(hh1, fpool3, mw1, mb1, 256, 512, 1);
  k_bnfeat3<<<dim3(512,3),32,0,stream>>>(hh1, hh1, g1, bb1, 512);
  k_mlp<<<dim3(2,96),256,0,stream>>>(hh2, hh1, mw2, mb2, 512, 512, 1);
  k_bnfeat3<<<dim3(512,3),32,0,stream>>>(hh2, hh2, g2, bb2, 512);
  k_mlp<<<dim3(1,96),256,0,stream>>>(hh3, hh2, mw3, mb3, 512, 128, 1);
  k_bnfeat3<<<dim3(128,3),32,0,stream>>>(hh3, hh3, g3, bb3, 128);
  k_score96<<<1,96,0,stream>>>(sc, hh3, mw4, mb4);
  k_out<<<1,32,0,stream>>>((float*)d_out, sc);
}

// Round 16
// 2163.906 us; speedup vs baseline: 1.5935x; 1.2950x over previous
//
#include <hip/hip_runtime.h>
#include <hip/hip_bf16.h>

#define Bc 32
#define NPGc 290
#define Nn 9280
#define Ec 74240
#define LPc 900
#define INFc 75
#define Dd 128
#define HKc 768
#define LQ 885
#define S1 904
#define S2 896
#define S3 888
#define LP128 132
#define NT 78          // upper-triangle 64x64 tiles of 768x768
#define TSZ 4096       // 64*64

__global__ void k_sentinel(float* out, float val){
  int t = threadIdx.x;
  if (t < 128) out[t] = val;
}

// ---------------- GCN ----------------
__global__ void k_h0(float* __restrict__ h0, const float* __restrict__ nh, const float* __restrict__ Wi){
  int n = blockIdx.x, j = threadIdx.x;
  __shared__ float arow[INFc];
  if (j < INFc) arow[j] = nh[(size_t)n*INFc + j];
  __syncthreads();
  float s = 0.f;
  #pragma unroll 5
  for (int k=0;k<INFc;k++) s += arow[k]*Wi[(size_t)k*Dd + j];
  h0[(size_t)n*Dd + j] = s;
}

__global__ void k_build_adj(float* __restrict__ A, const int* __restrict__ src, const int* __restrict__ dst){
  int e = blockIdx.x*blockDim.x + threadIdx.x;
  if (e >= Ec) return;
  int s = src[e], d = dst[e];
  int b = d / NPGc;
  int dl = d - b*NPGc, sl = s - b*NPGc;
  atomicAdd(&A[((size_t)b*NPGc + dl)*NPGc + sl], 1.f);
}

// batched over 3 branches: z = branch, layer l fixed per launch
__global__ void k_gcn_b(float* __restrict__ outb, size_t ostride,
                        const float* __restrict__ inb, size_t istride,
                        const float* __restrict__ A,
                        const float* __restrict__ Wall, const float* __restrict__ ball,
                        const float* __restrict__ Wrall, const float* __restrict__ brall,
                        int l){
  int g = blockIdx.z;
  int b = blockIdx.y;
  int i0 = blockIdx.x*8;
  int j = threadIdx.x;  // 128
  const float* h = inb + (size_t)g*istride;
  float* out = outb + (size_t)g*ostride;
  size_t wo = (size_t)(g*3 + l);
  const float* W  = Wall  + wo*Dd*Dd;
  const float* bv = ball  + wo*Dd;
  const float* Wr = Wrall + wo*Dd*Dd;
  const float* br = brall + wo*Dd;
  __shared__ float arow[8][NPGc];
  __shared__ float ar[8][Dd], hr[8][Dd];
  for (int idx=j; idx<8*NPGc; idx+=128){
    int r=idx/NPGc, c=idx-r*NPGc;
    arow[r][c] = (i0+r<NPGc) ? A[((size_t)b*NPGc+i0+r)*NPGc+c] : 0.f;
  }
  for (int idx=j; idx<8*Dd; idx+=128){
    int r=idx>>7, k=idx&127;
    hr[r][k] = (i0+r<NPGc) ? h[((size_t)b*NPGc+i0+r)*Dd+k] : 0.f;
  }
  __syncthreads();
  float acc[8]={};
  const float* hb = h + (size_t)b*NPGc*Dd + j;
  for (int c=0;c<NPGc;c++){
    float hv = hb[(size_t)c*Dd];
    #pragma unroll
    for (int r=0;r<8;r++) acc[r] += arow[r][c]*hv;
  }
  #pragma unroll
  for (int r=0;r<8;r++) ar[r][j] = acc[r];
  __syncthreads();
  float s1[8], s2[8];
  float bj = bv[j], brj = br[j];
  #pragma unroll
  for (int r=0;r<8;r++){ s1[r]=bj; s2[r]=brj; }
  for (int k=0;k<Dd;k++){
    float wk = W[(size_t)k*Dd+j], wrk = Wr[(size_t)k*Dd+j];
    #pragma unroll
    for (int r=0;r<8;r++){ s1[r] += ar[r][k]*wk; s2[r] += hr[r][k]*wrk; }
  }
  int nr = NPGc - i0; if (nr > 8) nr = 8;
  for (int r=0;r<nr;r++)
    out[((size_t)b*NPGc+i0+r)*Dd + j] = fmaxf(s1[r],0.f) + fmaxf(s2[r],0.f);
}

// ---------------- ProteinCNN ----------------
__global__ void k_embed(float* __restrict__ x, const int* __restrict__ vp, const float* __restrict__ emb){
  int t = blockIdx.x*blockDim.x + threadIdx.x;
  int d = blockIdx.y, b = blockIdx.z;
  if (t >= LPc) return;
  int tok = vp[b*LPc + t];
  x[((size_t)b*Dd + d)*LPc + t] = emb[(size_t)tok*Dd + d];
}

__global__ void k_wT(float* __restrict__ wT, const float* __restrict__ w, int KW){
  int idx = blockIdx.x*256 + threadIdx.x;
  int tot = Dd*Dd*KW;
  if (idx >= tot) return;
  int o = idx & 127; int rest = idx >> 7;
  wT[(size_t)rest*Dd + o] = w[((size_t)o*Dd + rest/KW)*KW + (rest % KW)];
}

// conv GEMM: M=128(o) x N=64(t), 8x4/thread; contiguous LDS stores (conflict-free)
template<int KW>
__global__ void k_convg2(float* __restrict__ y, const float* __restrict__ x, const float* __restrict__ wT,
                         const float* __restrict__ cb, const float* __restrict__ scale,
                         const float* __restrict__ shift, int Lin, int Lout, int XS, int YS, int cbo){
  int b = blockIdx.y;
  int t0 = blockIdx.x*64;
  __shared__ float As[16][LP128], Bs[16][64];
  int tid=threadIdx.x, tx=tid&15, ty=tid>>4;
  int ldr=tid>>4, ldc4=(tid&15)*4;
  float acc[8][4]={};
  const int KT = Dd*KW;
  for (int k0=0; k0<KT; k0+=16){
    // As: two contiguous float4 sweeps (lane-stride 4 -> all 32 banks)
    #pragma unroll
    for (int it=0; it<2; it++){
      int lin = (it*256 + tid) << 2;   // 0..2047
      int row = lin >> 7, col = lin & 127;
      *(float4*)&As[row][col] = *(const float4*)(wT + (size_t)(k0+row)*Dd + col);
    }
    // Bs: build in regs, single contiguous float4 store
    {
      int kr = k0+ldr; int i = kr/KW, k = kr - i*KW;
      float sc_ = scale ? scale[i] : 1.f;
      float sh_ = shift ? shift[i] : 0.f;
      const float* xr = x + ((size_t)b*Dd + i)*XS + t0 + k + ldc4;
      int tb = t0 + k + ldc4;
      float4 bv;
      bv.x = (tb+0 < Lin) ? xr[0]*sc_+sh_ : 0.f;
      bv.y = (tb+1 < Lin) ? xr[1]*sc_+sh_ : 0.f;
      bv.z = (tb+2 < Lin) ? xr[2]*sc_+sh_ : 0.f;
      bv.w = (tb+3 < Lin) ? xr[3]*sc_+sh_ : 0.f;
      *(float4*)&Bs[ldr][ldc4] = bv;
    }
    __syncthreads();
    #pragma unroll
    for (int kk=0;kk<16;kk++){
      float a[8], bb[4];
      *(float4*)&a[0] = *(const float4*)&As[kk][ty*4];
      *(float4*)&a[4] = *(const float4*)&As[kk][64+ty*4];
      *(float4*)bb = *(const float4*)&Bs[kk][tx*4];
      #pragma unroll
      for (int i2=0;i2<8;i2++)
        #pragma unroll
        for (int j2=0;j2<4;j2++) acc[i2][j2] += a[i2]*bb[j2];
    }
    __syncthreads();
  }
  int t = t0 + tx*4;
  #pragma unroll
  for (int i2=0;i2<8;i2++){
    int o = (i2<4) ? ty*4+i2 : 64+ty*4+(i2-4);
    float bias = cb[cbo+o];
    float* yp = y + ((size_t)b*Dd+o)*YS + t;
    if (t+3 < Lout){
      float4 v;
      v.x=fmaxf(acc[i2][0]+bias,0.f); v.y=fmaxf(acc[i2][1]+bias,0.f);
      v.z=fmaxf(acc[i2][2]+bias,0.f); v.w=fmaxf(acc[i2][3]+bias,0.f);
      *(float4*)yp = v;
    } else {
      for (int j2=0;j2<4;j2++) if (t+j2 < Lout) yp[j2] = fmaxf(acc[i2][j2]+bias,0.f);
    }
  }
}

// stats -> scale/shift (BN fold)
__global__ void k_bnc_stats2(float* __restrict__ scale, float* __restrict__ shift,
                             const float* __restrict__ y, int Lout, int YS,
                             const float* __restrict__ g, const float* __restrict__ bb, int go){
  int c = blockIdx.x;
  float s=0.f, ss=0.f;
  int cnt = Bc*Lout;
  for (int i = threadIdx.x; i < cnt; i += blockDim.x){
    int b = i / Lout, t = i - b*Lout;
    float v = y[((size_t)b*Dd+c)*YS + t];
    s += v; ss += v*v;
  }
  __shared__ float rs[256], rss[256];
  rs[threadIdx.x]=s; rss[threadIdx.x]=ss; __syncthreads();
  for (int st=128; st>0; st>>=1){
    if (threadIdx.x<st){ rs[threadIdx.x]+=rs[threadIdx.x+st]; rss[threadIdx.x]+=rss[threadIdx.x+st]; }
    __syncthreads();
  }
  if (threadIdx.x==0){
    float m = rs[0]/cnt; float v = rss[0]/cnt - m*m; if (v<0.f) v=0.f;
    float r = rsqrtf(v+1e-5f);
    float scl = r*g[go+c];
    scale[c] = scl;
    shift[c] = bb[go+c] - m*scl;
  }
}

// ---------------- BAN Gram path: 64x64 / 4x4 (no spill), Gq packed triangle ----------------
__global__ void k_qgemm_tile(float* __restrict__ qc, const float* __restrict__ x,
                             const float* __restrict__ W, const float* __restrict__ bias,
                             const float* __restrict__ scale, const float* __restrict__ shift,
                             int gbase){
  int bl = blockIdx.z, b = gbase + bl;
  int m0 = blockIdx.y*64;
  int n0 = blockIdx.x*64;
  __shared__ float As[16][64], Bs[16][64];
  int tid = threadIdx.x;
  int tx = tid & 15, ty = tid >> 4;
  int ldr = tid >> 4, ldc = (tid & 15)*4;
  float acc[4][4] = {};
  for (int k0 = 0; k0 < Dd; k0 += 16){
    int d = k0 + ldr;
    float sc_ = scale[d], sh_ = shift[d];
    const float* xrow = x + ((size_t)b*Dd + d)*S3 + m0 + ldc;
    int mb = m0 + ldc;
    float4 a4;
    a4.x = (mb+0 < LQ) ? xrow[0]*sc_+sh_ : 0.f;
    a4.y = (mb+1 < LQ) ? xrow[1]*sc_+sh_ : 0.f;
    a4.z = (mb+2 < LQ) ? xrow[2]*sc_+sh_ : 0.f;
    a4.w = (mb+3 < LQ) ? xrow[3]*sc_+sh_ : 0.f;
    *(float4*)&As[ldr][ldc] = a4;
    *(float4*)&Bs[ldr][ldc] = *(const float4*)(W + (size_t)d*HKc + n0 + ldc);
    __syncthreads();
    #pragma unroll
    for (int kk=0; kk<16; kk++){
      float a[4], bb[4];
      *(float4*)a  = *(const float4*)&As[kk][ty*4];
      *(float4*)bb = *(const float4*)&Bs[kk][tx*4];
      #pragma unroll
      for (int i=0;i<4;i++)
        #pragma unroll
        for (int j=0;j<4;j++) acc[i][j] += a[i]*bb[j];
    }
    __syncthreads();
  }
  #pragma unroll
  for (int i=0;i<4;i++){
    int m = m0 + ty*4 + i;
    if (m >= LQ) continue;
    int n = n0 + tx*4;
    float4 b4 = *(const float4*)(bias + n);
    float4 o;
    o.x = fmaxf(acc[i][0] + b4.x, 0.f);
    o.y = fmaxf(acc[i][1] + b4.y, 0.f);
    o.z = fmaxf(acc[i][2] + b4.z, 0.f);
    o.w = fmaxf(acc[i][3] + b4.w, 0.f);
    *(float4*)(qc + ((size_t)bl*LQ + m)*HKc + n) = o;
  }
}

__global__ void k_colsum_q(float* __restrict__ S, const float* __restrict__ X, int gbase){
  int j = blockIdx.x*256 + threadIdx.x;
  int bl = blockIdx.y;
  if (j >= HKc) return;
  const float* p = X + (size_t)bl*LQ*HKc + j;
  float s=0.f;
  for (int t=0;t<LQ;t++) s += p[(size_t)t*HKc];
  S[(gbase+bl)*HKc + j] = s;
}

// Gq packed: tile tl of graph bg at Gp[(bg*NT+tl)*TSZ], local 64x64 row-major
__global__ void k_gram_sym(float* __restrict__ Gp, const float* __restrict__ X, int gbase){
  int bl = blockIdx.y, bg = gbase + bl;
  int tl0 = blockIdx.x;
  int tl = tl0; int ti = 0;
  while (tl >= 12-ti){ tl -= 12-ti; ti++; }
  int tj = ti + tl;
  int r0 = ti*64, c0 = tj*64;
  const float* Xb = X + (size_t)bl*LQ*HKc;
  float* Gb = Gp + ((size_t)bg*NT + tl0)*TSZ;
  __shared__ float As[16][64], Bs[16][64];
  int tid = threadIdx.x;
  int tx = tid & 15, ty = tid >> 4;
  int ldr = tid >> 4, ldc = (tid & 15)*4;
  float acc[4][4] = {};
  for (int t0=0; t0<LQ; t0+=16){
    float4 av = make_float4(0.f,0.f,0.f,0.f), bv4 = make_float4(0.f,0.f,0.f,0.f);
    if (t0+ldr < LQ){
      const float* row = Xb + (size_t)(t0+ldr)*HKc;
      av  = *(const float4*)(row + r0 + ldc);
      bv4 = *(const float4*)(row + c0 + ldc);
    }
    *(float4*)&As[ldr][ldc] = av;
    *(float4*)&Bs[ldr][ldc] = bv4;
    __syncthreads();
    #pragma unroll
    for (int tt=0; tt<16; tt++){
      float a[4], bb[4];
      *(float4*)a  = *(const float4*)&As[tt][ty*4];
      *(float4*)bb = *(const float4*)&Bs[tt][tx*4];
      #pragma unroll
      for (int i=0;i<4;i++)
        #pragma unroll
        for (int j=0;j<4;j++) acc[i][j] += a[i]*bb[j];
    }
    __syncthreads();
  }
  for (int i=0;i<4;i++){
    int rl = ty*4 + i;
    *(float4*)(Gb + rl*64 + tx*4) =
      make_float4(acc[i][0],acc[i][1],acc[i][2],acc[i][3]);
  }
}

__global__ void k_vgemm8(float* __restrict__ v, const float* __restrict__ vd,
                         const float* __restrict__ W, const float* __restrict__ bias){
  int j = blockIdx.x*256 + threadIdx.x;
  int r0 = blockIdx.y*8;
  __shared__ float xr[8][Dd];
  for (int idx=threadIdx.x; idx<8*Dd; idx+=256){
    int r = idx>>7, k = idx&127;
    xr[r][k] = vd[(size_t)(r0 + r)*Dd + k];
  }
  __syncthreads();
  float acc[8];
  float bj = bias[j];
  #pragma unroll
  for (int r=0;r<8;r++) acc[r]=bj;
  for (int k=0;k<Dd;k++){
    float wk = W[(size_t)k*HKc+j];
    #pragma unroll
    for (int r=0;r<8;r++) acc[r] += xr[r][k]*wk;
  }
  #pragma unroll
  for (int r=0;r<8;r++)
    v[(size_t)(r0+r)*HKc + j] = fmaxf(acc[r],0.f);
}

__global__ void k_colsum_v(float* __restrict__ S, const float* __restrict__ X){
  int j = blockIdx.x*blockDim.x + threadIdx.x;
  int bl = blockIdx.y;
  if (j >= HKc) return;
  const float* p = X + (size_t)bl*NPGc*HKc + j;
  float s=0.f;
  for (int t=0;t<NPGc;t++) s += p[(size_t)t*HKc];
  S[bl*HKc + j] = s;
}

// gramf over packed upper-triangle tiles
__global__ void k_gramf_sym(float* __restrict__ f, const float* __restrict__ V,
                            const float* __restrict__ Gp, const float* __restrict__ hm){
  int bg = blockIdx.z;
  int tl0 = blockIdx.x;
  int tl = tl0; int ti = 0;
  while (tl >= 12-ti){ tl -= 12-ti; ti++; }
  int tj = ti + tl;
  int r0 = ti*64, c0 = tj*64;
  int offdiag = (ti != tj);
  const float* Vb = V + (size_t)bg*NPGc*HKc;
  __shared__ float As[16][64], Bs[16][64];
  __shared__ float wc[64], wr[64];
  int tid = threadIdx.x;
  int tx = tid & 15, ty = tid >> 4;
  int ldr = tid >> 4, ldc = (tid & 15)*4;
  if (tid < 64) wc[tid] = hm[c0+tid] + hm[HKc + c0 + tid];
  else if (tid < 128) wr[tid-64] = hm[r0+tid-64] + hm[HKc + r0 + tid-64];
  float acc[4][4] = {};
  for (int t0=0; t0<NPGc; t0+=16){
    float4 av = make_float4(0.f,0.f,0.f,0.f), bv4 = make_float4(0.f,0.f,0.f,0.f);
    if (t0+ldr < NPGc){
      const float* row = Vb + (size_t)(t0+ldr)*HKc;
      av  = *(const float4*)(row + r0 + ldc);
      bv4 = *(const float4*)(row + c0 + ldc);
    }
    *(float4*)&As[ldr][ldc] = av;
    *(float4*)&Bs[ldr][ldc] = bv4;
    __syncthreads();
    #pragma unroll
    for (int tt=0; tt<16; tt++){
      float a[4], bb[4];
      *(float4*)a  = *(const float4*)&As[tt][ty*4];
      *(float4*)bb = *(const float4*)&Bs[tt][tx*4];
      #pragma unroll
      for (int i=0;i<4;i++)
        #pragma unroll
        for (int j=0;j<4;j++) acc[i][j] += a[i]*bb[j];
    }
    __syncthreads();
  }
  const float* gqb = Gp + ((size_t)bg*NT + tl0)*TSZ;
  float w0 = wc[tx*4+0], w1 = wc[tx*4+1], w2 = wc[tx*4+2], w3 = wc[tx*4+3];
  float colp[4] = {0.f,0.f,0.f,0.f};
  #pragma unroll
  for (int i=0;i<4;i++){
    int rl = ty*4 + i;
    int r = r0 + rl;
    const float4 g4 = *(const float4*)(gqb + rl*64 + tx*4);
    float s = acc[i][0]*w0*g4.x + acc[i][1]*w1*g4.y
            + acc[i][2]*w2*g4.z + acc[i][3]*w3*g4.w;
    s += __shfl_xor(s, 1); s += __shfl_xor(s, 2);
    s += __shfl_xor(s, 4); s += __shfl_xor(s, 8);
    if (tx==0) atomicAdd(&f[bg*HKc + r], s);
    if (offdiag){
      float wri = wr[rl];
      colp[0] += acc[i][0]*wri*g4.x;
      colp[1] += acc[i][1]*wri*g4.y;
      colp[2] += acc[i][2]*wri*g4.z;
      colp[3] += acc[i][3]*wri*g4.w;
    }
  }
  if (offdiag){
    #pragma unroll
    for (int j=0;j<4;j++){
      colp[j] += __shfl_xor(colp[j], 16);
      colp[j] += __shfl_xor(colp[j], 32);
    }
    if ((tid & 48) == 0){
      #pragma unroll
      for (int j=0;j<4;j++)
        atomicAdd(&f[bg*HKc + c0 + tx*4 + j], colp[j]);
    }
  }
}

// batched pool over 3 views
__global__ void k_pool3(float* __restrict__ fp, const float* __restrict__ f3,
                        const float* __restrict__ Sv3, const float* __restrict__ Sq,
                        const float* __restrict__ hb){
  int idx = blockIdx.x*256 + threadIdx.x;
  if (idx >= 3*Bc*256) return;
  int v = idx >> 13;
  int rem = idx & 8191;
  int b = rem >> 8, c = rem & 255;
  const float* f = f3 + (size_t)v*Bc*HKc;
  const float* Sv = Sv3 + (size_t)v*Bc*HKc;
  float hbs = hb[0] + hb[1];
  float s = 0.f;
  #pragma unroll
  for (int r=0;r<3;r++){
    int k = c*3 + r;
    s += f[b*HKc + k] + hbs*Sv[b*HKc + k]*Sq[b*HKc + k];
  }
  fp[idx] = s;
}

__global__ void k_bnfeat3(float* __restrict__ y, const float* __restrict__ x, const float* __restrict__ g,
                          const float* __restrict__ bb, int C){
  int c = blockIdx.x; int v = blockIdx.y; int b = threadIdx.x;
  __shared__ float buf[32];
  __shared__ float mv[2];
  int row = v*32 + b;
  float val = x[(size_t)row*C + c];
  buf[b] = val;
  __syncthreads();
  if (b == 0){
    float s = 0.f;
    for (int i=0;i<32;i++) s += buf[i];
    float m = s/32.f;
    float vs = 0.f;
    for (int i=0;i<32;i++){ float d = buf[i]-m; vs += d*d; }
    mv[0] = m; mv[1] = vs/32.f;
  }
  __syncthreads();
  y[(size_t)row*C + c] = (val - mv[0])*rsqrtf(mv[1]+1e-5f)*g[c] + bb[c];
}

__global__ void k_mlp(float* __restrict__ out, const float* __restrict__ in, const float* __restrict__ W,
                      const float* __restrict__ bias, int K, int Nc, int doRelu){
  int b = blockIdx.y;
  int j = blockIdx.x*blockDim.x + threadIdx.x;
  __shared__ float xr[512];
  for (int k=threadIdx.x; k<K; k+=blockDim.x) xr[k] = in[(size_t)b*K+k];
  __syncthreads();
  if (j >= Nc) return;
  float s = bias[j];
  for (int k=0;k<K;k++) s += xr[k]*W[(size_t)k*Nc + j];
  if (doRelu) s = fmaxf(s, 0.f);
  out[(size_t)b*Nc + j] = s;
}

__global__ void k_score96(float* __restrict__ sc, const float* __restrict__ h, const float* __restrict__ w,
                          const float* __restrict__ bb){
  int b = threadIdx.x; if (b>=96) return;
  float s = bb[0];
  for (int k=0;k<Dd;k++) s += h[(size_t)b*Dd+k]*w[k];
  sc[b] = s;
}

__global__ void k_out(float* __restrict__ out, const float* __restrict__ scores){
  int t = threadIdx.x;
  __shared__ float loss_s;
  if (t == 0){
    float sn1[32], sn2[32];
    for (int i=0;i<32;i++){
      float a = scores[32+i]; sn1[i] = a / fmaxf(fabsf(a), 1e-12f);
      float c = scores[64+i]; sn2[i] = c / fmaxf(fabsf(c), 1e-12f);
    }
    float acc = 0.f;
    for (int i=0;i<32;i++){
      float mx = -1e30f;
      for (int j=0;j<32;j++) mx = fmaxf(mx, sn1[i]*sn2[j]);
      float se = 0.f;
      for (int j=0;j<32;j++) se += expf(sn1[i]*sn2[j]-mx);
      acc += sn1[i]*sn2[i] - (mx + logf(se));
    }
    loss_s = -acc/32.f;
  }
  __syncthreads();
  out[t*4+0] = scores[t];
  out[t*4+1] = scores[32+t];
  out[t*4+2] = scores[64+t];
  out[t*4+3] = loss_s;
}

extern "C" void kernel_launch(void* const* d_in, const int* in_sizes, int n_in,
                              void* d_out, int out_size, void* d_ws, size_t ws_size,
                              hipStream_t stream){
  static const int exp_sizes[38] = {
    Nn*INFc, Ec, Ec, Bc*LPc, INFc*Dd,
    9*Dd*Dd, 9*Dd, 9*Dd*Dd, 9*Dd,
    26*Dd, Dd*Dd*3, Dd*Dd*6, Dd*Dd*9, 3*Dd, 3*Dd, 3*Dd,
    Dd*HKc, HKc, Dd*HKc, HKc, 2*HKc, 2, 256, 256,
    256*512, 512, 512*512, 512, 512*128, 128, 128, 1,
    512, 512, 512, 512, 128, 128 };
  if (n_in != 38){ k_sentinel<<<1,128,0,stream>>>((float*)d_out, 2000.f + n_in); return; }
  for (int i=0;i<38;i++){
    if (in_sizes[i] != exp_sizes[i]){
      k_sentinel<<<1,128,0,stream>>>((float*)d_out, 1000.f + i); return;
    }
  }

  const float* node_h=(const float*)d_in[0];
  const int*  esrc  =(const int*)d_in[1];
  const int*  edst  =(const int*)d_in[2];
  const int*  vp    =(const int*)d_in[3];
  const float* W_init=(const float*)d_in[4];
  const float* gcn_W =(const float*)d_in[5];
  const float* gcn_b =(const float*)d_in[6];
  const float* gcn_Wr=(const float*)d_in[7];
  const float* gcn_br=(const float*)d_in[8];
  const float* emb   =(const float*)d_in[9];
  const float* c1w=(const float*)d_in[10];
  const float* c2w=(const float*)d_in[11];
  const float* c3w=(const float*)d_in[12];
  const float* cbv=(const float*)d_in[13];
  const float* bng=(const float*)d_in[14];
  const float* bnb=(const float*)d_in[15];
  const float* Wv =(const float*)d_in[16];
  const float* bvv=(const float*)d_in[17];
  const float* Wq =(const float*)d_in[18];
  const float* bq =(const float*)d_in[19];
  const float* hmat =(const float*)d_in[20];
  const float* hbias=(const float*)d_in[21];
  const float* bang =(const float*)d_in[22];
  const float* banb =(const float*)d_in[23];
  const float* mw1=(const float*)d_in[24]; const float* mb1=(const float*)d_in[25];
  const float* mw2=(const float*)d_in[26]; const float* mb2=(const float*)d_in[27];
  const float* mw3=(const float*)d_in[28]; const float* mb3=(const float*)d_in[29];
  const float* mw4=(const float*)d_in[30]; const float* mb4=(const float*)d_in[31];
  const float* g1=(const float*)d_in[32]; const float* bb1=(const float*)d_in[33];
  const float* g2=(const float*)d_in[34]; const float* bb2=(const float*)d_in[35];
  const float* g3=(const float*)d_in[36]; const float* bb3=(const float*)d_in[37];

  float* ws = (float*)d_ws;
  size_t off = 0;
  auto alloc = [&](size_t n){ float* p = ws + off; off += n; return p; };

  const size_t NDsz = (size_t)Nn*Dd;              // 1,187,840
  const size_t CNNBP = (size_t)Bc*Dd*S1;          // 3,702,784
  const size_t ADJ  = (size_t)Bc*NPGc*NPGc;       // 2,691,200
  const size_t QB8  = (size_t)8*LQ*HKc;           // 5,437,440
  const size_t VB   = (size_t)Bc*NPGc*HKc;        // 7,127,040
  // arena = max(CNN 2*CNNBP, q CNNBP+QB8, GCN 7*NDsz+ADJ, BAN 4*NDsz+VB)
  size_t ARENA = 7*NDsz + ADJ;                    // 11,006,080
  if (ARENA < 4*NDsz + VB) ARENA = 4*NDsz + VB;   // 11,878,400
  if (ARENA < CNNBP + QB8) ARENA = CNNBP + QB8;
  if (ARENA < 2*CNNBP) ARENA = 2*CNNBP;

  // smalls
  float* Sq   = alloc((size_t)Bc*HKc);
  float* Sv3  = alloc((size_t)3*Bc*HKc);
  float* fbuf3= alloc((size_t)3*Bc*HKc);
  float* fpool3=alloc((size_t)3*Bc*256);
  float* hh1  = alloc((size_t)96*512);
  float* hh2  = alloc((size_t)96*512);
  float* hh3  = alloc((size_t)96*128);
  float* sc   = alloc(96);
  float* scl1 = alloc(128); float* shf1 = alloc(128);
  float* scl2 = alloc(128); float* shf2 = alloc(128);
  float* scl3 = alloc(128); float* shf3 = alloc(128);
  float* wT1 = alloc((size_t)Dd*Dd*3);
  float* wT2 = alloc((size_t)Dd*Dd*6);
  float* wT3 = alloc((size_t)Dd*Dd*9);
  float* Gqp = alloc((size_t)Bc*NT*TSZ);          // packed triangle: 10,223,616
  float* arena = alloc(ARENA);
  // total ≈ 0.60M + 10.22M + 11.88M ≈ 22.7M floats ≈ 90.8 MiB (well under proven 108)

  // phase views
  float* cnnA = arena;                  // CNN out (S3-padded) lives here
  float* cnnB = arena + CNNBP;
  float* qbuf = arena + CNNBP;          // 8-graph full-length q
  float* h0b  = arena;                  // [0, NDsz)
  float* Bb   = arena + NDsz;           // 3 bufs [NDsz, 4*NDsz)
  float* Cb   = arena + 4*NDsz;         // 3 bufs [4N, 7N)
  float* Adj  = arena + 7*NDsz;         // [7N, 7N+ADJ)
  float* vbuf = arena + 4*NDsz;         // BAN phase: [4N, 4N+VB) (C and Adj dead)

  // NOTE: cnnA overlaps h0b range; CNN+q phases complete before GCN writes h0b.

  // ---- conv weight transposes ----
  k_wT<<<(Dd*Dd*3+255)/256,256,0,stream>>>(wT1, c1w, 3);
  k_wT<<<(Dd*Dd*6+255)/256,256,0,stream>>>(wT2, c2w, 6);
  k_wT<<<(Dd*Dd*9+255)/256,256,0,stream>>>(wT3, c3w, 9);

  // ---- ProteinCNN (BN folded into next stage-in) ----
  k_embed<<<dim3((LPc+127)/128, Dd, Bc),128,0,stream>>>(cnnB, vp, emb);
  k_convg2<3><<<dim3(15,Bc),256,0,stream>>>(cnnA, cnnB, wT1, cbv, nullptr, nullptr, 900, 898, 900, S1, 0);
  k_bnc_stats2<<<Dd,256,0,stream>>>(scl1, shf1, cnnA, 898, S1, bng, bnb, 0);
  k_convg2<6><<<dim3(14,Bc),256,0,stream>>>(cnnB, cnnA, wT2, cbv, scl1, shf1, 898, 893, S1, S2, 128);
  k_bnc_stats2<<<Dd,256,0,stream>>>(scl2, shf2, cnnB, 893, S2, bng, bnb, 128);
  k_convg2<9><<<dim3(14,Bc),256,0,stream>>>(cnnA, cnnB, wT3, cbv, scl2, shf2, 893, 885, S2, S3, 256);
  k_bnc_stats2<<<Dd,256,0,stream>>>(scl3, shf3, cnnA, 885, S3, bng, bnb, 256);

  // ---- q branch: 4 passes of 8 graphs, single-shot packed Gq ----
  for (int gb = 0; gb < Bc; gb += 8){
    k_qgemm_tile<<<dim3(12,(LQ+63)/64,8),256,0,stream>>>(qbuf, cnnA, Wq, bq, scl3, shf3, gb);
    k_colsum_q<<<dim3(3,8),256,0,stream>>>(Sq, qbuf, gb);
    k_gram_sym<<<dim3(NT,8),256,0,stream>>>(Gqp, qbuf, gb);
  }

  // ---- dense adjacency ----
  hipMemsetAsync(Adj, 0, ADJ*sizeof(float), stream);
  k_build_adj<<<(Ec+255)/256,256,0,stream>>>(Adj, esrc, edst);

  hipMemsetAsync(fbuf3, 0, (size_t)3*Bc*HKc*sizeof(float), stream);

  // ---- GCN: h0 once, 3 branches batched per layer ----
  k_h0<<<Nn,Dd,0,stream>>>(h0b, node_h, W_init);
  k_gcn_b<<<dim3(37,Bc,3),128,0,stream>>>(Bb, NDsz, h0b, 0,    Adj, gcn_W, gcn_b, gcn_Wr, gcn_br, 0);
  k_gcn_b<<<dim3(37,Bc,3),128,0,stream>>>(Cb, NDsz, Bb, NDsz,  Adj, gcn_W, gcn_b, gcn_Wr, gcn_br, 1);
  k_gcn_b<<<dim3(37,Bc,3),128,0,stream>>>(Bb, NDsz, Cb, NDsz,  Adj, gcn_W, gcn_b, gcn_Wr, gcn_br, 2);

  // ---- BAN per view (32 graphs per launch) ----
  for (int g=0; g<3; g++){
    k_vgemm8<<<dim3(3,(Bc*NPGc)/8),256,0,stream>>>(vbuf, Bb + (size_t)g*NDsz, Wv, bvv);
    k_colsum_v<<<dim3(3,Bc),256,0,stream>>>(Sv3 + (size_t)g*Bc*HKc, vbuf);
    k_gramf_sym<<<dim3(NT,1,Bc),256,0,stream>>>(fbuf3 + (size_t)g*Bc*HKc, vbuf, Gqp, hmat);
  }

  // ---- batched tail over 3 views (96 rows) ----
  k_pool3<<<(3*Bc*256+255)/256,256,0,stream>>>(fpool3, fbuf3, Sv3, Sq, hbias);
  k_bnfeat3<<<dim3(256,3),32,0,stream>>>(fpool3, fpool3, bang, banb, 256);
  k_mlp<<<dim3(2,96),256,0,stream>>>(hh1, fpool3, mw1, mb1, 256, 512, 1);
  k_bnfeat3<<<dim3(512,3),32,0,stream>>>(hh1, hh1, g1, bb1, 512);
  k_mlp<<<dim3(2,96),256,0,stream>>>(hh2, hh1, mw2, mb2, 512, 512, 1);
  k_bnfeat3<<<dim3(512,3),32,0,stream>>>(hh2, hh2, g2, bb2, 512);
  k_mlp<<<dim3(1,96),256,0,stream>>>(hh3, hh2, mw3, mb3, 512, 128, 1);
  k_bnfeat3<<<dim3(128,3),32,0,stream>>>(hh3, hh3, g3, bb3, 128);
  k_score96<<<1,96,0,stream>>>(sc, hh3, mw4, mb4);
  k_out<<<1,32,0,stream>>>((float*)d_out, sc);
}